// Round 8
// baseline (292.714 us; speedup 1.0000x reference)
//
#include <hip/hip_runtime.h>
#include <cstdint>
#include <cstddef>

// Problem constants (shapes fixed by the reference)
#define F_IN   128
#define HC1    64    // heads1*ch1 = 8*8
#define CH2_   16
#define NB     64    // batch graphs
#define BUKPAD 8192  // per-bucket padding (avg fill ~4350 for E=1.6M, N=100K)

__global__ void fill_f32(float* __restrict__ p, float v, int n) {
  int i = blockIdx.x * blockDim.x + threadIdx.x;
  int stride = gridDim.x * blockDim.x;
  for (; i < n; i += stride) p[i] = v;
}

// ---------------- DPP cross-lane reductions (full-rate VALU, no LDS pipe) -----
template<int CTRL>
__device__ __forceinline__ float dpp_add(float v) {
  int j = __builtin_amdgcn_update_dpp(0, __float_as_int(v), CTRL, 0xF, 0xF, true);
  return v + __int_as_float(j);
}
__device__ __forceinline__ float sum16_dpp(float v) {  // sum over each 16-lane row
  v = dpp_add<0xB1>(v);
  v = dpp_add<0x4E>(v);
  v = dpp_add<0x141>(v);
  v = dpp_add<0x140>(v);  // row_mirror
  return v;
}

// ---------------- Layer-1 dual GEMM (M=64): known-good round-4 version --------
template<int K, int M, int BM, bool PAD>
__global__ void gemm_dual(const float* __restrict__ x,
                          const float* __restrict__ Wa, const float* __restrict__ ba,
                          const float* __restrict__ Wb, const float* __restrict__ bb,
                          float* __restrict__ ya, float* __restrict__ yb, int n) {
  constexpr int KP = PAD ? K + 4 : K;
  constexpr int GROUPS = 256 / M;
  constexpr int NN = BM / GROUPS;
  __shared__ float xs[BM * KP];
  const int t = threadIdx.x;
  const int node0 = blockIdx.x * BM;
  for (int i = t; i < BM * (K / 4); i += 256) {
    int row = i / (K / 4);
    int kk  = (i % (K / 4)) * 4;
    int node = node0 + row;
    float4 v = make_float4(0.f, 0.f, 0.f, 0.f);
    if (node < n) v = *reinterpret_cast<const float4*>(x + (size_t)node * K + kk);
    *reinterpret_cast<float4*>(xs + row * KP + kk) = v;
  }
  __syncthreads();
  const int col = t % M;
  const int ng  = t / M;
  float accA[NN], accB[NN];
  const float biasA = ba[col], biasB = bb[col];
#pragma unroll
  for (int i = 0; i < NN; ++i) { accA[i] = biasA; accB[i] = biasB; }
  for (int k = 0; k < K; k += 4) {
    float wa0 = Wa[(k + 0) * M + col], wa1 = Wa[(k + 1) * M + col];
    float wa2 = Wa[(k + 2) * M + col], wa3 = Wa[(k + 3) * M + col];
    float wb0 = Wb[(k + 0) * M + col], wb1 = Wb[(k + 1) * M + col];
    float wb2 = Wb[(k + 2) * M + col], wb3 = Wb[(k + 3) * M + col];
#pragma unroll
    for (int nn = 0; nn < NN; ++nn) {
      float4 xv = *reinterpret_cast<const float4*>(xs + (ng * NN + nn) * KP + k);
      accA[nn] += xv.x * wa0 + xv.y * wa1 + xv.z * wa2 + xv.w * wa3;
      accB[nn] += xv.x * wb0 + xv.y * wb1 + xv.z * wb2 + xv.w * wb3;
    }
  }
#pragma unroll
  for (int nn = 0; nn < NN; ++nn) {
    int node = node0 + ng * NN + nn;
    if (node < n) {
      ya[(size_t)node * M + col] = accA[nn];
      yb[(size_t)node * M + col] = accB[nn];
    }
  }
}

// ---------------- CSR build via 2-pass bucketed counting sort -----------------

__global__ void bucket_scatter(const int* __restrict__ ei, int E, int E2,
                               int* __restrict__ gcnt, int* __restrict__ gbuk) {
  __shared__ int hbase[512];
  __shared__ int hcnt[512];
  const int t = threadIdx.x;
  for (int i = t; i < 512; i += 256) { hbase[i] = 0; hcnt[i] = 0; }
  __syncthreads();
  int srcs[32], dsts[32];
  const int tile0 = blockIdx.x * 8192;
#pragma unroll
  for (int k = 0; k < 32; ++k) {
    int e = tile0 + k * 256 + t;          // coalesced
    int s = -1, d = 0;
    if (e < E2) {
      if (e < E) { s = ei[e]; d = ei[E + e]; } else { s = d = e - E; }
      atomicAdd(&hbase[d >> 8], 1);       // LDS atomic
    }
    srcs[k] = s; dsts[k] = d;
  }
  __syncthreads();
  for (int i = t; i < 512; i += 256) {    // reserve this block's run per bucket
    int c = hbase[i];
    hbase[i] = (c > 0) ? atomicAdd(&gcnt[i], c) : 0;
  }
  __syncthreads();
#pragma unroll
  for (int k = 0; k < 32; ++k) {
    if (srcs[k] >= 0) {
      int d = dsts[k], b = d >> 8;
      int r = atomicAdd(&hcnt[b], 1);     // LDS atomic: rank within (block,bucket)
      int pl = hbase[b] + r;
      if (pl < BUKPAD) gbuk[(size_t)b * BUKPAD + pl] = (srcs[k] << 8) | (d & 255);
    }
  }
}

__global__ void bucket_prefix(const int* __restrict__ gcnt, int nbuk,
                              int* __restrict__ gbase, int* __restrict__ row_start, int n) {
  int lane = threadIdx.x;  // 64 threads
  int carry = 0;
  for (int basei = 0; basei < nbuk; basei += 64) {
    int i = basei + lane;
    int orig = (i < nbuk) ? gcnt[i] : 0;
    int v = orig;
    for (int off = 1; off < 64; off <<= 1) {
      int u = __shfl_up(v, off);
      if (lane >= off) v += u;
    }
    if (i < nbuk) gbase[i] = carry + v - orig;
    carry += __shfl(v, 63);
  }
  if (lane == 0) row_start[n] = carry;    // == E2
}

__global__ void bucket_csr(const int* __restrict__ gcnt, const int* __restrict__ gbase,
                           const int* __restrict__ gbuk,
                           int* __restrict__ row_start, int* __restrict__ csr_src, int n) {
  const int b = blockIdx.x;
  const int t = threadIdx.x;
  const int node0 = b << 8;
  const int cntb = min(gcnt[b], BUKPAD);
  const int base = gbase[b];
  const int* buk = gbuk + (size_t)b * BUKPAD;
  __shared__ int h[256];
  __shared__ int off[256];
  h[t] = 0;
  __syncthreads();
  for (int i = t; i < cntb; i += 256) atomicAdd(&h[buk[i] & 255], 1);
  __syncthreads();
  off[t] = h[t];
  __syncthreads();
  for (int o = 1; o < 256; o <<= 1) {     // inclusive Hillis-Steele scan
    int u = (t >= o) ? off[t - o] : 0;
    __syncthreads();
    off[t] += u;
    __syncthreads();
  }
  int excl = off[t] - h[t];
  if (node0 + t < n) row_start[node0 + t] = base + excl;
  h[t] = excl;                            // running counter per node
  __syncthreads();
  for (int i = t; i < cntb; i += 256) {
    int p = buk[i];
    int r = atomicAdd(&h[p & 255], 1);    // LDS atomic
    csr_src[base + r] = p >> 8;           // store within ~17KB L2-hot window
  }
}

// ---------------- Fused layer 1 + layer-2 linear transforms -------------------
// float4 lane layout: one wave per node; lane = (g,q), g=lane>>4 edge slot,
// q=lane&15 holds channels 4q..4q+3 (head q>>1). Per 4-edge chunk: 1 csr dword
// load + 1 dwordx4 gather/lane (16B), dot4 + pair-DPP logit, shfl_xor(16/32)
// chunk max, 1.25 exp/edge. Tail edges masked via logit=-3e38 (ex->0).
// ~11 instr/edge vs ~30 for the round-7 scalar layout (VALU-issue-bound).
__global__ void fused_layer1(const int* __restrict__ row_start, const int* __restrict__ csr_src,
                             const float* __restrict__ xl, const float* __restrict__ xr,
                             const float* __restrict__ att, const float* __restrict__ bias,
                             const float* __restrict__ Wl2, const float* __restrict__ bl2,
                             const float* __restrict__ Wr2, const float* __restrict__ br2,
                             float* __restrict__ xl2, float* __restrict__ xr2, int n) {
  __shared__ float Ws2[64 * 32];   // [l][j]: j<16 -> Wl2 col j, j>=16 -> Wr2 col j-16
  __shared__ float b2s[32];
  const int t = threadIdx.x;
  for (int i = t; i < 64 * 16; i += 256) {
    int l = i >> 4, j = i & 15;
    Ws2[l * 32 + j]      = Wl2[i];
    Ws2[l * 32 + 16 + j] = Wr2[i];
  }
  if (t < 16) { b2s[t] = bl2[t]; b2s[16 + t] = br2[t]; }
  __syncthreads();

  const int node = blockIdx.x * 4 + (t >> 6);
  if (node >= n) return;
  const int lane = t & 63;
  const int g = lane >> 4;            // edge slot 0..3
  const int q = lane & 15;            // channels 4q..4q+3, head q>>1
  const float4 attv = *reinterpret_cast<const float4*>(att + q * 4);
  const float4 xrv  = *reinterpret_cast<const float4*>(xr + (size_t)node * 64 + q * 4);
  const int beg = row_start[node];
  const int total = row_start[node + 1] - beg;   // >= 1 (self loop)
  const float NEGB = -3.0e38f;
  float m = NEGB, den = 0.0f;
  float4 acc = make_float4(0.f, 0.f, 0.f, 0.f);

  for (int p0 = 0; p0 < total; p0 += 4) {
    int pe = p0 + g;
    bool valid = pe < total;
    int s = csr_src[beg + (valid ? pe : 0)];
    float4 xv = *reinterpret_cast<const float4*>(xl + (size_t)s * 64 + q * 4);
    float a0 = xv.x + xrv.x; a0 = fmaxf(a0, 0.2f * a0);   // leaky_relu(.,0.2)
    float a1 = xv.y + xrv.y; a1 = fmaxf(a1, 0.2f * a1);
    float a2 = xv.z + xrv.z; a2 = fmaxf(a2, 0.2f * a2);
    float a3 = xv.w + xrv.w; a3 = fmaxf(a3, 0.2f * a3);
    float part = a0 * attv.x + a1 * attv.y + a2 * attv.z + a3 * attv.w;
    float v = dpp_add<0xB1>(part);    // pair-sum -> full head logit on lanes 2h,2h+1
    v = valid ? v : NEGB;
    float mv = fmaxf(v, __shfl_xor(v, 16));
    mv = fmaxf(mv, __shfl_xor(mv, 32));           // max over the 4 edge slots
    float nm = fmaxf(m, mv);
    float scale = __expf(m - nm);                 // first chunk: exp(NEGB-nm)=0
    float ex = __expf(v - nm);                    // 0 for masked slots
    den = den * scale + ex;
    acc.x = acc.x * scale + ex * xv.x;
    acc.y = acc.y * scale + ex * xv.y;
    acc.z = acc.z * scale + ex * xv.z;
    acc.w = acc.w * scale + ex * xv.w;
    m = nm;
  }
  // combine the 4 edge slots (pairs already share den; don't pair-reduce)
  acc.x += __shfl_xor(acc.x, 16); acc.y += __shfl_xor(acc.y, 16);
  acc.z += __shfl_xor(acc.z, 16); acc.w += __shfl_xor(acc.w, 16);
  acc.x += __shfl_xor(acc.x, 32); acc.y += __shfl_xor(acc.y, 32);
  acc.z += __shfl_xor(acc.z, 32); acc.w += __shfl_xor(acc.w, 32);
  den += __shfl_xor(den, 16);
  den += __shfl_xor(den, 32);
  const float inv = 1.0f / (den + 1e-16f);
  const float4 bi = *reinterpret_cast<const float4*>(bias + q * 4);
  float o0 = acc.x * inv + bi.x; o0 = o0 > 0.f ? o0 : __expf(o0) - 1.0f;  // elu
  float o1 = acc.y * inv + bi.y; o1 = o1 > 0.f ? o1 : __expf(o1) - 1.0f;
  float o2 = acc.z * inv + bi.z; o2 = o2 > 0.f ? o2 : __expf(o2) - 1.0f;
  float o3 = acc.w * inv + bi.w; o3 = o3 > 0.f ? o3 : __expf(o3) - 1.0f;

  // redistribute h1 to one channel per lane (channel = lane)
  int srcl = lane >> 2;
  float c0 = __shfl(o0, srcl);
  float c1 = __shfl(o1, srcl);
  float c2 = __shfl(o2, srcl);
  float c3 = __shfl(o3, srcl);
  int r = lane & 3;
  float o = (r == 0) ? c0 : (r == 1) ? c1 : (r == 2) ? c2 : c3;

  // in-wave layer-2 transforms: out[j] = sum_l o_l * Ws2[l][j]
  const int j    = lane & 31;
  const int half = lane >> 5;              // 0: l=0..31, 1: l=32..63
  float part2 = 0.0f;
#pragma unroll 8
  for (int l = 0; l < 32; ++l) {
    int src = half * 32 + l;
    float ov = __shfl(o, src);
    part2 += ov * Ws2[src * 32 + j];
  }
  part2 += __shfl_xor(part2, 32);          // combine the two halves
  if (lane < 16)      xl2[(size_t)node * 16 + j]        = part2 + b2s[j];
  else if (lane < 32) xr2[(size_t)node * 16 + (j - 16)] = part2 + b2s[j];
}

// ---------------- Fused layer 2 (unchanged) -----------------------------------
__global__ void fused_layer2(const int* __restrict__ row_start, const int* __restrict__ csr_src,
                             const float* __restrict__ xl, const float* __restrict__ xr,
                             const float* __restrict__ att, const float* __restrict__ bias,
                             float* __restrict__ out, int n) {
  int node = blockIdx.x * 16 + (threadIdx.x >> 4);
  if (node >= n) return;
  int c = threadIdx.x & 15;
  const float attv = att[c];
  const float xrv  = xr[(size_t)node * 16 + c];
  const int beg = row_start[node], end = row_start[node + 1];
  float m = -__builtin_huge_valf();
  float den = 0.0f, acc = 0.0f;
  int p = beg;
  for (; p + 4 <= end; p += 4) {
    int s0 = csr_src[p + 0], s1 = csr_src[p + 1];
    int s2 = csr_src[p + 2], s3 = csr_src[p + 3];
    float x0 = xl[(size_t)s0 * 16 + c];
    float x1 = xl[(size_t)s1 * 16 + c];
    float x2 = xl[(size_t)s2 * 16 + c];
    float x3 = xl[(size_t)s3 * 16 + c];
    float a0 = x0 + xrv; a0 = a0 > 0.f ? a0 : 0.2f * a0;
    float a1 = x1 + xrv; a1 = a1 > 0.f ? a1 : 0.2f * a1;
    float a2 = x2 + xrv; a2 = a2 > 0.f ? a2 : 0.2f * a2;
    float a3 = x3 + xrv; a3 = a3 > 0.f ? a3 : 0.2f * a3;
    float v0 = sum16_dpp(a0 * attv);
    float v1 = sum16_dpp(a1 * attv);
    float v2 = sum16_dpp(a2 * attv);
    float v3 = sum16_dpp(a3 * attv);
    float nm = fmaxf(m, fmaxf(fmaxf(v0, v1), fmaxf(v2, v3)));
    float scale = __expf(m - nm);
    float e0 = __expf(v0 - nm), e1 = __expf(v1 - nm);
    float e2 = __expf(v2 - nm), e3 = __expf(v3 - nm);
    den = den * scale + ((e0 + e1) + (e2 + e3));
    acc = acc * scale + ((e0 * x0 + e1 * x1) + (e2 * x2 + e3 * x3));
    m = nm;
  }
  for (; p < end; ++p) {
    int s = csr_src[p];
    float xv = xl[(size_t)s * 16 + c];
    float a = xv + xrv; a = a > 0.f ? a : 0.2f * a;
    float v = sum16_dpp(a * attv);
    float nm = fmaxf(m, v);
    float scale = __expf(m - nm);
    float ex = __expf(v - nm);
    den = den * scale + ex;
    acc = acc * scale + ex * xv;
    m = nm;
  }
  out[(size_t)node * 16 + c] = acc / (den + 1e-16f) + bias[c];   // no elu after conv2
}

// ---------------- Pooling + classifier ---------------------------------------

__global__ void pool_kernel(const float* __restrict__ h2, const int* __restrict__ batch,
                            float* __restrict__ sums, float* __restrict__ cnts, int n) {
  __shared__ float ls[NB * CH2_];
  __shared__ float lc[NB];
  for (int i = threadIdx.x; i < NB * CH2_; i += blockDim.x) ls[i] = 0.0f;
  for (int i = threadIdx.x; i < NB; i += blockDim.x) lc[i] = 0.0f;
  __syncthreads();
  int total = n * 16;
  int stride = gridDim.x * blockDim.x;
  for (int i = blockIdx.x * blockDim.x + threadIdx.x; i < total; i += stride) {
    int node = i >> 4, c = i & 15;
    int b = batch[node];
    atomicAdd(&ls[b * 16 + c], h2[i]);
    if (c == 0) atomicAdd(&lc[b], 1.0f);
  }
  __syncthreads();
  for (int i = threadIdx.x; i < NB * CH2_; i += blockDim.x)
    if (ls[i] != 0.0f) atomicAdd(&sums[i], ls[i]);
  for (int i = threadIdx.x; i < NB; i += blockDim.x)
    if (lc[i] != 0.0f) atomicAdd(&cnts[i], lc[i]);
}

__global__ void classifier(const float* __restrict__ sums, const float* __restrict__ cnts,
                           const float* __restrict__ Wc, const float* __restrict__ bc,
                           float* __restrict__ out) {
  int b = threadIdx.x;
  if (b >= NB) return;
  float cnt = cnts[b];
  cnt = cnt > 1.0f ? cnt : 1.0f;
  float acc = 0.0f;
  for (int c = 0; c < 16; ++c) {
    float p = sums[b * 16 + c] / cnt;
    out[NB + b * 16 + c] = p;   // pooled, output 1
    acc += p * Wc[c];
  }
  out[b] = acc + bc[0];         // out, output 0
}

extern "C" void kernel_launch(void* const* d_in, const int* in_sizes, int n_in,
                              void* d_out, int out_size, void* d_ws, size_t ws_size,
                              hipStream_t stream) {
  const float* x     = (const float*)d_in[0];
  const int*   ei    = (const int*)d_in[1];
  const int*   batch = (const int*)d_in[2];
  const float* Wl1   = (const float*)d_in[3];
  const float* bl1   = (const float*)d_in[4];
  const float* Wr1   = (const float*)d_in[5];
  const float* br1   = (const float*)d_in[6];
  const float* att1  = (const float*)d_in[7];
  const float* bias1 = (const float*)d_in[8];
  const float* Wl2   = (const float*)d_in[9];
  const float* bl2   = (const float*)d_in[10];
  const float* Wr2   = (const float*)d_in[11];
  const float* br2   = (const float*)d_in[12];
  const float* att2  = (const float*)d_in[13];
  const float* bias2 = (const float*)d_in[14];
  const float* Wc    = (const float*)d_in[15];
  const float* bc    = (const float*)d_in[16];
  float* out = (float*)d_out;

  const int N  = in_sizes[0] / F_IN;
  const int E  = in_sizes[1] / 2;
  const int E2 = E + N;
  const int nbuk = (N + 255) >> 8;   // 391 for N=100K (<=512 assumed)

  // Workspace layout (~90 MB)
  float* ws   = (float*)d_ws;
  float* xl1  = ws;                            // N*64
  float* xr1  = xl1 + (size_t)N * 64;          // N*64
  float* xl2  = xr1 + (size_t)N * 64;          // N*16
  float* xr2  = xl2 + (size_t)N * 16;          // N*16
  float* h2   = xr2 + (size_t)N * 16;          // N*16
  int* irow   = (int*)(h2 + (size_t)N * 16);   // N+1
  int* icsr   = irow + (N + 1);                // E2
  int* gcnt   = icsr + E2;                     // 512
  int* gbase  = gcnt + 512;                    // 512+1
  int* gbuk   = gbase + 513 + 2;               // nbuk*BUKPAD
  float* sums = (float*)(gbuk + (size_t)nbuk * BUKPAD);  // NB*16
  float* cnts = sums + NB * CH2_;              // NB

  // ---- CSR build (2-pass bucketed counting sort) ----
  fill_f32<<<1, 256, 0, stream>>>((float*)gcnt, 0.0f, 512);
  bucket_scatter<<<(E2 + 8191) / 8192, 256, 0, stream>>>(ei, E, E2, gcnt, gbuk);
  bucket_prefix<<<1, 64, 0, stream>>>(gcnt, nbuk, gbase, irow, N);
  bucket_csr<<<nbuk, 256, 0, stream>>>(gcnt, gbase, gbuk, irow, icsr, N);

  // ---- layer 1 GEMM ----
  gemm_dual<F_IN, HC1, 64, false><<<(N + 63) / 64, 256, 0, stream>>>(
      x, Wl1, bl1, Wr1, br1, xl1, xr1, N);

  // ---- fused layer 1 + layer-2 linear transforms ----
  fused_layer1<<<(N + 3) / 4, 256, 0, stream>>>(
      irow, icsr, xl1, xr1, att1, bias1, Wl2, bl2, Wr2, br2, xl2, xr2, N);

  // ---- fused layer 2 ----
  fused_layer2<<<(N + 15) / 16, 256, 0, stream>>>(irow, icsr, xl2, xr2, att2, bias2, h2, N);

  // ---- pooling + classifier ----
  fill_f32<<<1, 256, 0, stream>>>(sums, 0.0f, NB * CH2_ + NB);
  pool_kernel<<<256, 256, 0, stream>>>(h2, batch, sums, cnts, N);
  classifier<<<1, 64, 0, stream>>>(sums, cnts, Wc, bc, out);
}

// Round 9
// 286.104 us; speedup vs baseline: 1.0231x; 1.0231x over previous
//
#include <hip/hip_runtime.h>
#include <cstdint>
#include <cstddef>

// Problem constants (shapes fixed by the reference)
#define F_IN   128
#define HC1    64    // heads1*ch1 = 8*8
#define CH2_   16
#define NB     64    // batch graphs
#define BUKPAD 8192  // per-bucket padding (avg fill ~4350 for E=1.6M, N=100K)

__global__ void fill_f32(float* __restrict__ p, float v, int n) {
  int i = blockIdx.x * blockDim.x + threadIdx.x;
  int stride = gridDim.x * blockDim.x;
  for (; i < n; i += stride) p[i] = v;
}

__device__ __forceinline__ unsigned short f2bf_rne(float v) {
  unsigned int u = __float_as_uint(v);
  unsigned int r = (u + 0x7FFFu + ((u >> 16) & 1u)) >> 16;   // round-nearest-even
  return (unsigned short)r;
}
__device__ __forceinline__ float bf2f(unsigned short b) {
  return __uint_as_float((unsigned int)b << 16);              // exact
}

// ---------------- DPP cross-lane reductions (full-rate VALU, no LDS pipe) -----
template<int CTRL>
__device__ __forceinline__ float dpp_add(float v) {
  int j = __builtin_amdgcn_update_dpp(0, __float_as_int(v), CTRL, 0xF, 0xF, true);
  return v + __int_as_float(j);
}
__device__ __forceinline__ float sum16_dpp(float v) {  // sum over each 16-lane row
  v = dpp_add<0xB1>(v);
  v = dpp_add<0x4E>(v);
  v = dpp_add<0x141>(v);
  v = dpp_add<0x140>(v);  // row_mirror
  return v;
}

// ---------------- Layer-1 dual GEMM: xl out as bf16, xr out as fp32 -----------
// (round-4 structure; bf16 xl halves both GEMM write traffic and the
//  fused_layer1 gather payload)
__global__ void gemm_dual_l1(const float* __restrict__ x,
                             const float* __restrict__ Wa, const float* __restrict__ ba,
                             const float* __restrict__ Wb, const float* __restrict__ bb,
                             unsigned short* __restrict__ ya, float* __restrict__ yb, int n) {
  constexpr int K = F_IN, M = HC1, BM = 64, NN = 16;  // GROUPS=4, NN=BM/GROUPS
  __shared__ float xs[BM * K];
  const int t = threadIdx.x;
  const int node0 = blockIdx.x * BM;
  for (int i = t; i < BM * (K / 4); i += 256) {
    int row = i / (K / 4);
    int kk  = (i % (K / 4)) * 4;
    int node = node0 + row;
    float4 v = make_float4(0.f, 0.f, 0.f, 0.f);
    if (node < n) v = *reinterpret_cast<const float4*>(x + (size_t)node * K + kk);
    *reinterpret_cast<float4*>(xs + row * K + kk) = v;
  }
  __syncthreads();
  const int col = t % M;
  const int ng  = t / M;
  float accA[NN], accB[NN];
  const float biasA = ba[col], biasB = bb[col];
#pragma unroll
  for (int i = 0; i < NN; ++i) { accA[i] = biasA; accB[i] = biasB; }
  for (int k = 0; k < K; k += 4) {
    float wa0 = Wa[(k + 0) * M + col], wa1 = Wa[(k + 1) * M + col];
    float wa2 = Wa[(k + 2) * M + col], wa3 = Wa[(k + 3) * M + col];
    float wb0 = Wb[(k + 0) * M + col], wb1 = Wb[(k + 1) * M + col];
    float wb2 = Wb[(k + 2) * M + col], wb3 = Wb[(k + 3) * M + col];
#pragma unroll
    for (int nn = 0; nn < NN; ++nn) {
      float4 xv = *reinterpret_cast<const float4*>(xs + (ng * NN + nn) * K + k);
      accA[nn] += xv.x * wa0 + xv.y * wa1 + xv.z * wa2 + xv.w * wa3;
      accB[nn] += xv.x * wb0 + xv.y * wb1 + xv.z * wb2 + xv.w * wb3;
    }
  }
#pragma unroll
  for (int nn = 0; nn < NN; ++nn) {
    int node = node0 + ng * NN + nn;
    if (node < n) {
      ya[(size_t)node * M + col] = f2bf_rne(accA[nn]);
      yb[(size_t)node * M + col] = accB[nn];
    }
  }
}

// ---------------- CSR build via 2-pass bucketed counting sort -----------------

__global__ void bucket_scatter(const int* __restrict__ ei, int E, int E2,
                               int* __restrict__ gcnt, int* __restrict__ gbuk) {
  __shared__ int hbase[512];
  __shared__ int hcnt[512];
  const int t = threadIdx.x;
  for (int i = t; i < 512; i += 256) { hbase[i] = 0; hcnt[i] = 0; }
  __syncthreads();
  int srcs[32], dsts[32];
  const int tile0 = blockIdx.x * 8192;
#pragma unroll
  for (int k = 0; k < 32; ++k) {
    int e = tile0 + k * 256 + t;          // coalesced
    int s = -1, d = 0;
    if (e < E2) {
      if (e < E) { s = ei[e]; d = ei[E + e]; } else { s = d = e - E; }
      atomicAdd(&hbase[d >> 8], 1);       // LDS atomic
    }
    srcs[k] = s; dsts[k] = d;
  }
  __syncthreads();
  for (int i = t; i < 512; i += 256) {    // reserve this block's run per bucket
    int c = hbase[i];
    hbase[i] = (c > 0) ? atomicAdd(&gcnt[i], c) : 0;
  }
  __syncthreads();
#pragma unroll
  for (int k = 0; k < 32; ++k) {
    if (srcs[k] >= 0) {
      int d = dsts[k], b = d >> 8;
      int r = atomicAdd(&hcnt[b], 1);     // LDS atomic: rank within (block,bucket)
      int pl = hbase[b] + r;
      if (pl < BUKPAD) gbuk[(size_t)b * BUKPAD + pl] = (srcs[k] << 8) | (d & 255);
    }
  }
}

__global__ void bucket_prefix(const int* __restrict__ gcnt, int nbuk,
                              int* __restrict__ gbase, int* __restrict__ row_start, int n) {
  int lane = threadIdx.x;  // 64 threads
  int carry = 0;
  for (int basei = 0; basei < nbuk; basei += 64) {
    int i = basei + lane;
    int orig = (i < nbuk) ? gcnt[i] : 0;
    int v = orig;
    for (int off = 1; off < 64; off <<= 1) {
      int u = __shfl_up(v, off);
      if (lane >= off) v += u;
    }
    if (i < nbuk) gbase[i] = carry + v - orig;
    carry += __shfl(v, 63);
  }
  if (lane == 0) row_start[n] = carry;    // == E2
}

__global__ void bucket_csr(const int* __restrict__ gcnt, const int* __restrict__ gbase,
                           const int* __restrict__ gbuk,
                           int* __restrict__ row_start, int* __restrict__ csr_src, int n) {
  const int b = blockIdx.x;
  const int t = threadIdx.x;
  const int node0 = b << 8;
  const int cntb = min(gcnt[b], BUKPAD);
  const int base = gbase[b];
  const int* buk = gbuk + (size_t)b * BUKPAD;
  __shared__ int h[256];
  __shared__ int off[256];
  h[t] = 0;
  __syncthreads();
  for (int i = t; i < cntb; i += 256) atomicAdd(&h[buk[i] & 255], 1);
  __syncthreads();
  off[t] = h[t];
  __syncthreads();
  for (int o = 1; o < 256; o <<= 1) {     // inclusive Hillis-Steele scan
    int u = (t >= o) ? off[t - o] : 0;
    __syncthreads();
    off[t] += u;
    __syncthreads();
  }
  int excl = off[t] - h[t];
  if (node0 + t < n) row_start[node0 + t] = base + excl;
  h[t] = excl;                            // running counter per node
  __syncthreads();
  for (int i = t; i < cntb; i += 256) {
    int p = buk[i];
    int r = atomicAdd(&h[p & 255], 1);    // LDS atomic
    csr_src[base + r] = p >> 8;           // store within ~17KB L2-hot window
  }
}

// ---------------- Fused layer 1 + layer-2 linear transforms -------------------
// float4-channel lane layout (g=lane>>4 edge slot, q=lane&15 -> channels
// 4q..4q+3), bf16 xl gathers (ushort4, 128B/edge = 2 lines), and NO online
// max: logits are structurally bounded (|logit| <= sum|att|*|a| ~ 8, exp<=3e3,
// den<=5e4 -- no fp32 overflow; softmax is shift-invariant so this matches the
// reference exactly up to rounding). Removing the max kills the serial
// rescale chain -> chunks fully independent, gathers pipeline freely.
__global__ void fused_layer1(const int* __restrict__ row_start, const int* __restrict__ csr_src,
                             const unsigned short* __restrict__ xl, const float* __restrict__ xr,
                             const float* __restrict__ att, const float* __restrict__ bias,
                             const float* __restrict__ Wl2, const float* __restrict__ bl2,
                             const float* __restrict__ Wr2, const float* __restrict__ br2,
                             float* __restrict__ xl2, float* __restrict__ xr2, int n) {
  __shared__ float Ws2[64 * 32];   // [l][j]: j<16 -> Wl2 col j, j>=16 -> Wr2 col j-16
  __shared__ float b2s[32];
  const int t = threadIdx.x;
  for (int i = t; i < 64 * 16; i += 256) {
    int l = i >> 4, j = i & 15;
    Ws2[l * 32 + j]      = Wl2[i];
    Ws2[l * 32 + 16 + j] = Wr2[i];
  }
  if (t < 16) { b2s[t] = bl2[t]; b2s[16 + t] = br2[t]; }
  __syncthreads();

  const int node = blockIdx.x * 4 + (t >> 6);
  if (node >= n) return;
  const int lane = t & 63;
  const int g = lane >> 4;            // edge slot 0..3
  const int q = lane & 15;            // channels 4q..4q+3, head q>>1
  const float4 attv = *reinterpret_cast<const float4*>(att + q * 4);
  const float4 xrv  = *reinterpret_cast<const float4*>(xr + (size_t)node * 64 + q * 4);
  const int beg = row_start[node];
  const int total = row_start[node + 1] - beg;   // >= 1 (self loop)
  const float NEGB = -3.0e38f;                   // masked slots: exp -> 0
  float den = 0.0f;
  float4 acc = make_float4(0.f, 0.f, 0.f, 0.f);

  for (int p0 = 0; p0 < total; p0 += 4) {
    int pe = p0 + g;
    bool valid = pe < total;
    int s = csr_src[beg + (valid ? pe : 0)];
    ushort4 us = *reinterpret_cast<const ushort4*>(xl + (size_t)s * 64 + q * 4);
    float xv0 = bf2f(us.x), xv1 = bf2f(us.y), xv2 = bf2f(us.z), xv3 = bf2f(us.w);
    float a0 = xv0 + xrv.x; a0 = fmaxf(a0, 0.2f * a0);   // leaky_relu(.,0.2)
    float a1 = xv1 + xrv.y; a1 = fmaxf(a1, 0.2f * a1);
    float a2 = xv2 + xrv.z; a2 = fmaxf(a2, 0.2f * a2);
    float a3 = xv3 + xrv.w; a3 = fmaxf(a3, 0.2f * a3);
    float part = a0 * attv.x + a1 * attv.y + a2 * attv.z + a3 * attv.w;
    float v = dpp_add<0xB1>(part);    // pair-sum -> full head logit on lanes 2h,2h+1
    float ex = __expf(valid ? v : NEGB);          // no max-subtraction needed
    den += ex;
    acc.x += ex * xv0;
    acc.y += ex * xv1;
    acc.z += ex * xv2;
    acc.w += ex * xv3;
  }
  // combine the 4 edge slots (pair lanes already share den)
  acc.x += __shfl_xor(acc.x, 16); acc.y += __shfl_xor(acc.y, 16);
  acc.z += __shfl_xor(acc.z, 16); acc.w += __shfl_xor(acc.w, 16);
  acc.x += __shfl_xor(acc.x, 32); acc.y += __shfl_xor(acc.y, 32);
  acc.z += __shfl_xor(acc.z, 32); acc.w += __shfl_xor(acc.w, 32);
  den += __shfl_xor(den, 16);
  den += __shfl_xor(den, 32);
  const float inv = 1.0f / (den + 1e-16f);
  const float4 bi = *reinterpret_cast<const float4*>(bias + q * 4);
  float o0 = acc.x * inv + bi.x; o0 = o0 > 0.f ? o0 : __expf(o0) - 1.0f;  // elu
  float o1 = acc.y * inv + bi.y; o1 = o1 > 0.f ? o1 : __expf(o1) - 1.0f;
  float o2 = acc.z * inv + bi.z; o2 = o2 > 0.f ? o2 : __expf(o2) - 1.0f;
  float o3 = acc.w * inv + bi.w; o3 = o3 > 0.f ? o3 : __expf(o3) - 1.0f;

  // redistribute h1 to one channel per lane (channel = lane)
  int srcl = lane >> 2;
  float c0 = __shfl(o0, srcl);
  float c1 = __shfl(o1, srcl);
  float c2 = __shfl(o2, srcl);
  float c3 = __shfl(o3, srcl);
  int r = lane & 3;
  float o = (r == 0) ? c0 : (r == 1) ? c1 : (r == 2) ? c2 : c3;

  // in-wave layer-2 transforms: out[j] = sum_l o_l * Ws2[l][j]
  const int j    = lane & 31;
  const int half = lane >> 5;              // 0: l=0..31, 1: l=32..63
  float part2 = 0.0f;
#pragma unroll 8
  for (int l = 0; l < 32; ++l) {
    int src = half * 32 + l;
    float ov = __shfl(o, src);
    part2 += ov * Ws2[src * 32 + j];
  }
  part2 += __shfl_xor(part2, 32);          // combine the two halves
  if (lane < 16)      xl2[(size_t)node * 16 + j]        = part2 + b2s[j];
  else if (lane < 32) xr2[(size_t)node * 16 + (j - 16)] = part2 + b2s[j];
}

// ---------------- Fused layer 2 (no online max; same bound argument) ----------
__global__ void fused_layer2(const int* __restrict__ row_start, const int* __restrict__ csr_src,
                             const float* __restrict__ xl, const float* __restrict__ xr,
                             const float* __restrict__ att, const float* __restrict__ bias,
                             float* __restrict__ out, int n) {
  int node = blockIdx.x * 16 + (threadIdx.x >> 4);
  if (node >= n) return;
  int c = threadIdx.x & 15;
  const float attv = att[c];
  const float xrv  = xr[(size_t)node * 16 + c];
  const int beg = row_start[node], end = row_start[node + 1];
  float den = 0.0f, acc = 0.0f;
  int p = beg;
  for (; p + 4 <= end; p += 4) {
    int s0 = csr_src[p + 0], s1 = csr_src[p + 1];
    int s2 = csr_src[p + 2], s3 = csr_src[p + 3];
    float x0 = xl[(size_t)s0 * 16 + c];
    float x1 = xl[(size_t)s1 * 16 + c];
    float x2 = xl[(size_t)s2 * 16 + c];
    float x3 = xl[(size_t)s3 * 16 + c];
    float a0 = x0 + xrv; a0 = a0 > 0.f ? a0 : 0.2f * a0;
    float a1 = x1 + xrv; a1 = a1 > 0.f ? a1 : 0.2f * a1;
    float a2 = x2 + xrv; a2 = a2 > 0.f ? a2 : 0.2f * a2;
    float a3 = x3 + xrv; a3 = a3 > 0.f ? a3 : 0.2f * a3;
    float e0 = __expf(sum16_dpp(a0 * attv));
    float e1 = __expf(sum16_dpp(a1 * attv));
    float e2 = __expf(sum16_dpp(a2 * attv));
    float e3 = __expf(sum16_dpp(a3 * attv));
    den += (e0 + e1) + (e2 + e3);
    acc += (e0 * x0 + e1 * x1) + (e2 * x2 + e3 * x3);
  }
  for (; p < end; ++p) {
    int s = csr_src[p];
    float xv = xl[(size_t)s * 16 + c];
    float a = xv + xrv; a = a > 0.f ? a : 0.2f * a;
    float ex = __expf(sum16_dpp(a * attv));
    den += ex;
    acc += ex * xv;
  }
  out[(size_t)node * 16 + c] = acc / (den + 1e-16f) + bias[c];   // no elu after conv2
}

// ---------------- Pooling + classifier ---------------------------------------

__global__ void pool_kernel(const float* __restrict__ h2, const int* __restrict__ batch,
                            float* __restrict__ sums, float* __restrict__ cnts, int n) {
  __shared__ float ls[NB * CH2_];
  __shared__ float lc[NB];
  for (int i = threadIdx.x; i < NB * CH2_; i += blockDim.x) ls[i] = 0.0f;
  for (int i = threadIdx.x; i < NB; i += blockDim.x) lc[i] = 0.0f;
  __syncthreads();
  int total = n * 16;
  int stride = gridDim.x * blockDim.x;
  for (int i = blockIdx.x * blockDim.x + threadIdx.x; i < total; i += stride) {
    int node = i >> 4, c = i & 15;
    int b = batch[node];
    atomicAdd(&ls[b * 16 + c], h2[i]);
    if (c == 0) atomicAdd(&lc[b], 1.0f);
  }
  __syncthreads();
  for (int i = threadIdx.x; i < NB * CH2_; i += blockDim.x)
    if (ls[i] != 0.0f) atomicAdd(&sums[i], ls[i]);
  for (int i = threadIdx.x; i < NB; i += blockDim.x)
    if (lc[i] != 0.0f) atomicAdd(&cnts[i], lc[i]);
}

__global__ void classifier(const float* __restrict__ sums, const float* __restrict__ cnts,
                           const float* __restrict__ Wc, const float* __restrict__ bc,
                           float* __restrict__ out) {
  int b = threadIdx.x;
  if (b >= NB) return;
  float cnt = cnts[b];
  cnt = cnt > 1.0f ? cnt : 1.0f;
  float acc = 0.0f;
  for (int c = 0; c < 16; ++c) {
    float p = sums[b * 16 + c] / cnt;
    out[NB + b * 16 + c] = p;   // pooled, output 1
    acc += p * Wc[c];
  }
  out[b] = acc + bc[0];         // out, output 0
}

extern "C" void kernel_launch(void* const* d_in, const int* in_sizes, int n_in,
                              void* d_out, int out_size, void* d_ws, size_t ws_size,
                              hipStream_t stream) {
  const float* x     = (const float*)d_in[0];
  const int*   ei    = (const int*)d_in[1];
  const int*   batch = (const int*)d_in[2];
  const float* Wl1   = (const float*)d_in[3];
  const float* bl1   = (const float*)d_in[4];
  const float* Wr1   = (const float*)d_in[5];
  const float* br1   = (const float*)d_in[6];
  const float* att1  = (const float*)d_in[7];
  const float* bias1 = (const float*)d_in[8];
  const float* Wl2   = (const float*)d_in[9];
  const float* bl2   = (const float*)d_in[10];
  const float* Wr2   = (const float*)d_in[11];
  const float* br2   = (const float*)d_in[12];
  const float* att2  = (const float*)d_in[13];
  const float* bias2 = (const float*)d_in[14];
  const float* Wc    = (const float*)d_in[15];
  const float* bc    = (const float*)d_in[16];
  float* out = (float*)d_out;

  const int N  = in_sizes[0] / F_IN;
  const int E  = in_sizes[1] / 2;
  const int E2 = E + N;
  const int nbuk = (N + 255) >> 8;   // 391 for N=100K (<=512 assumed)

  // Workspace layout
  float* ws   = (float*)d_ws;
  unsigned short* xl1 = (unsigned short*)ws;   // N*64 bf16
  float* xr1  = (float*)(xl1 + (size_t)N * 64);// N*64 fp32 (aligned: N*64*2 bytes)
  float* xl2  = xr1 + (size_t)N * 64;          // N*16
  float* xr2  = xl2 + (size_t)N * 16;          // N*16
  float* h2   = xr2 + (size_t)N * 16;          // N*16
  int* irow   = (int*)(h2 + (size_t)N * 16);   // N+1
  int* icsr   = irow + (N + 1);                // E2
  int* gcnt   = icsr + E2;                     // 512
  int* gbase  = gcnt + 512;                    // 512+1
  int* gbuk   = gbase + 513 + 2;               // nbuk*BUKPAD
  float* sums = (float*)(gbuk + (size_t)nbuk * BUKPAD);  // NB*16
  float* cnts = sums + NB * CH2_;              // NB

  // ---- CSR build (2-pass bucketed counting sort) ----
  fill_f32<<<1, 256, 0, stream>>>((float*)gcnt, 0.0f, 512);
  bucket_scatter<<<(E2 + 8191) / 8192, 256, 0, stream>>>(ei, E, E2, gcnt, gbuk);
  bucket_prefix<<<1, 64, 0, stream>>>(gcnt, nbuk, gbase, irow, N);
  bucket_csr<<<nbuk, 256, 0, stream>>>(gcnt, gbase, gbuk, irow, icsr, N);

  // ---- layer 1 GEMM (xl bf16, xr fp32) ----
  gemm_dual_l1<<<(N + 63) / 64, 256, 0, stream>>>(
      x, Wl1, bl1, Wr1, br1, xl1, xr1, N);

  // ---- fused layer 1 + layer-2 linear transforms ----
  fused_layer1<<<(N + 3) / 4, 256, 0, stream>>>(
      irow, icsr, xl1, xr1, att1, bias1, Wl2, bl2, Wr2, br2, xl2, xr2, N);

  // ---- fused layer 2 ----
  fused_layer2<<<(N + 15) / 16, 256, 0, stream>>>(irow, icsr, xl2, xr2, att2, bias2, h2, N);

  // ---- pooling + classifier ----
  fill_f32<<<1, 256, 0, stream>>>(sums, 0.0f, NB * CH2_ + NB);
  pool_kernel<<<256, 256, 0, stream>>>(h2, batch, sums, cnts, N);
  classifier<<<1, 64, 0, stream>>>(sums, cnts, Wc, bc, out);
}

// Round 10
// 264.893 us; speedup vs baseline: 1.1050x; 1.0801x over previous
//
#include <hip/hip_runtime.h>
#include <cstdint>
#include <cstddef>

// Problem constants (shapes fixed by the reference)
#define F_IN   128
#define HC1    64    // heads1*ch1 = 8*8
#define CH2_   16
#define NB     64    // batch graphs
#define BUKPAD 8192  // per-bucket padding (avg fill ~4350 for E=1.6M, N=100K)

__global__ void fill_f32(float* __restrict__ p, float v, int n) {
  int i = blockIdx.x * blockDim.x + threadIdx.x;
  int stride = gridDim.x * blockDim.x;
  for (; i < n; i += stride) p[i] = v;
}

__device__ __forceinline__ unsigned short f2bf_rne(float v) {
  unsigned int u = __float_as_uint(v);
  unsigned int r = (u + 0x7FFFu + ((u >> 16) & 1u)) >> 16;   // round-nearest-even
  return (unsigned short)r;
}
__device__ __forceinline__ float bf2f(unsigned short b) {
  return __uint_as_float((unsigned int)b << 16);              // exact
}

// ---------------- DPP cross-lane reductions (full-rate VALU, no LDS pipe) -----
template<int CTRL>
__device__ __forceinline__ float dpp_add(float v) {
  int j = __builtin_amdgcn_update_dpp(0, __float_as_int(v), CTRL, 0xF, 0xF, true);
  return v + __int_as_float(j);
}
__device__ __forceinline__ float sum16_dpp(float v) {  // sum over each 16-lane row
  v = dpp_add<0xB1>(v);
  v = dpp_add<0x4E>(v);
  v = dpp_add<0x141>(v);
  v = dpp_add<0x140>(v);  // row_mirror
  return v;
}

// ---------------- Layer-1 dual GEMM: xl out as bf16, xr out as fp32 -----------
__global__ void gemm_dual_l1(const float* __restrict__ x,
                             const float* __restrict__ Wa, const float* __restrict__ ba,
                             const float* __restrict__ Wb, const float* __restrict__ bb,
                             unsigned short* __restrict__ ya, float* __restrict__ yb, int n) {
  constexpr int K = F_IN, M = HC1, BM = 64, NN = 16;  // GROUPS=4, NN=BM/GROUPS
  __shared__ float xs[BM * K];
  const int t = threadIdx.x;
  const int node0 = blockIdx.x * BM;
  for (int i = t; i < BM * (K / 4); i += 256) {
    int row = i / (K / 4);
    int kk  = (i % (K / 4)) * 4;
    int node = node0 + row;
    float4 v = make_float4(0.f, 0.f, 0.f, 0.f);
    if (node < n) v = *reinterpret_cast<const float4*>(x + (size_t)node * K + kk);
    *reinterpret_cast<float4*>(xs + row * K + kk) = v;
  }
  __syncthreads();
  const int col = t % M;
  const int ng  = t / M;
  float accA[NN], accB[NN];
  const float biasA = ba[col], biasB = bb[col];
#pragma unroll
  for (int i = 0; i < NN; ++i) { accA[i] = biasA; accB[i] = biasB; }
  for (int k = 0; k < K; k += 4) {
    float wa0 = Wa[(k + 0) * M + col], wa1 = Wa[(k + 1) * M + col];
    float wa2 = Wa[(k + 2) * M + col], wa3 = Wa[(k + 3) * M + col];
    float wb0 = Wb[(k + 0) * M + col], wb1 = Wb[(k + 1) * M + col];
    float wb2 = Wb[(k + 2) * M + col], wb3 = Wb[(k + 3) * M + col];
#pragma unroll
    for (int nn = 0; nn < NN; ++nn) {
      float4 xv = *reinterpret_cast<const float4*>(xs + (ng * NN + nn) * K + k);
      accA[nn] += xv.x * wa0 + xv.y * wa1 + xv.z * wa2 + xv.w * wa3;
      accB[nn] += xv.x * wb0 + xv.y * wb1 + xv.z * wb2 + xv.w * wb3;
    }
  }
#pragma unroll
  for (int nn = 0; nn < NN; ++nn) {
    int node = node0 + ng * NN + nn;
    if (node < n) {
      ya[(size_t)node * M + col] = f2bf_rne(accA[nn]);
      yb[(size_t)node * M + col] = accB[nn];
    }
  }
}

// ---------------- CSR build via 2-pass bucketed counting sort -----------------

__global__ void bucket_scatter(const int* __restrict__ ei, int E, int E2,
                               int* __restrict__ gcnt, int* __restrict__ gbuk) {
  __shared__ int hbase[512];
  __shared__ int hcnt[512];
  const int t = threadIdx.x;
  for (int i = t; i < 512; i += 256) { hbase[i] = 0; hcnt[i] = 0; }
  __syncthreads();
  int srcs[32], dsts[32];
  const int tile0 = blockIdx.x * 8192;
#pragma unroll
  for (int k = 0; k < 32; ++k) {
    int e = tile0 + k * 256 + t;          // coalesced
    int s = -1, d = 0;
    if (e < E2) {
      if (e < E) { s = ei[e]; d = ei[E + e]; } else { s = d = e - E; }
      atomicAdd(&hbase[d >> 8], 1);       // LDS atomic
    }
    srcs[k] = s; dsts[k] = d;
  }
  __syncthreads();
  for (int i = t; i < 512; i += 256) {    // reserve this block's run per bucket
    int c = hbase[i];
    hbase[i] = (c > 0) ? atomicAdd(&gcnt[i], c) : 0;
  }
  __syncthreads();
#pragma unroll
  for (int k = 0; k < 32; ++k) {
    if (srcs[k] >= 0) {
      int d = dsts[k], b = d >> 8;
      int r = atomicAdd(&hcnt[b], 1);     // LDS atomic: rank within (block,bucket)
      int pl = hbase[b] + r;
      if (pl < BUKPAD) gbuk[(size_t)b * BUKPAD + pl] = (srcs[k] << 8) | (d & 255);
    }
  }
}

__global__ void bucket_prefix(const int* __restrict__ gcnt, int nbuk,
                              int* __restrict__ gbase, int* __restrict__ row_start, int n) {
  int lane = threadIdx.x;  // 64 threads
  int carry = 0;
  for (int basei = 0; basei < nbuk; basei += 64) {
    int i = basei + lane;
    int orig = (i < nbuk) ? gcnt[i] : 0;
    int v = orig;
    for (int off = 1; off < 64; off <<= 1) {
      int u = __shfl_up(v, off);
      if (lane >= off) v += u;
    }
    if (i < nbuk) gbase[i] = carry + v - orig;
    carry += __shfl(v, 63);
  }
  if (lane == 0) row_start[n] = carry;    // == E2
}

__global__ void bucket_csr(const int* __restrict__ gcnt, const int* __restrict__ gbase,
                           const int* __restrict__ gbuk,
                           int* __restrict__ row_start, int* __restrict__ csr_src, int n) {
  const int b = blockIdx.x;
  const int t = threadIdx.x;
  const int node0 = b << 8;
  const int cntb = min(gcnt[b], BUKPAD);
  const int base = gbase[b];
  const int* buk = gbuk + (size_t)b * BUKPAD;
  __shared__ int h[256];
  __shared__ int off[256];
  h[t] = 0;
  __syncthreads();
  for (int i = t; i < cntb; i += 256) atomicAdd(&h[buk[i] & 255], 1);
  __syncthreads();
  off[t] = h[t];
  __syncthreads();
  for (int o = 1; o < 256; o <<= 1) {     // inclusive Hillis-Steele scan
    int u = (t >= o) ? off[t - o] : 0;
    __syncthreads();
    off[t] += u;
    __syncthreads();
  }
  int excl = off[t] - h[t];
  if (node0 + t < n) row_start[node0 + t] = base + excl;
  h[t] = excl;                            // running counter per node
  __syncthreads();
  for (int i = t; i < cntb; i += 256) {
    int p = buk[i];
    int r = atomicAdd(&h[p & 255], 1);    // LDS atomic
    csr_src[base + r] = p >> 8;           // store within ~17KB L2-hot window
  }
}

// ---------------- Fused layer 1 + layer-2 linear transforms -------------------
// Latency-MLP restructure (rounds 7-9 were pinned at ~113us, latency-bound:
// VALU 54-80%, HBM 13-24%, dur invariant under both instruction and byte
// cuts). Changes vs round 9:
//  (a) coalesced csr window preload: 1 load covers 64 edges; chunk src ids
//      come from __shfl (bpermute, ~30cy, no global dependency in the chain);
//  (b) 2x chunk unroll: 8 edges (2 independent gathers) in flight per iter.
// Tail masked via min-clamp (address always valid) + exp(NEGB)=0.
__global__ void fused_layer1(const int* __restrict__ row_start, const int* __restrict__ csr_src,
                             const unsigned short* __restrict__ xl, const float* __restrict__ xr,
                             const float* __restrict__ att, const float* __restrict__ bias,
                             const float* __restrict__ Wl2, const float* __restrict__ bl2,
                             const float* __restrict__ Wr2, const float* __restrict__ br2,
                             float* __restrict__ xl2, float* __restrict__ xr2, int n) {
  __shared__ float Ws2[64 * 32];   // [l][j]: j<16 -> Wl2 col j, j>=16 -> Wr2 col j-16
  __shared__ float b2s[32];
  const int t = threadIdx.x;
  for (int i = t; i < 64 * 16; i += 256) {
    int l = i >> 4, j = i & 15;
    Ws2[l * 32 + j]      = Wl2[i];
    Ws2[l * 32 + 16 + j] = Wr2[i];
  }
  if (t < 16) { b2s[t] = bl2[t]; b2s[16 + t] = br2[t]; }
  __syncthreads();

  const int node = blockIdx.x * 4 + (t >> 6);
  if (node >= n) return;
  const int lane = t & 63;
  const int g = lane >> 4;            // edge slot 0..3 within a chunk
  const int q = lane & 15;            // channels 4q..4q+3, head q>>1
  const float4 attv = *reinterpret_cast<const float4*>(att + q * 4);
  const float4 xrv  = *reinterpret_cast<const float4*>(xr + (size_t)node * 64 + q * 4);
  const unsigned short* xlq = xl + q * 4;
  const int beg = row_start[node];
  const int total = row_start[node + 1] - beg;   // >= 1 (self loop)
  const float NEGB = -3.0e38f;                   // masked slots: exp -> 0
  float den = 0.0f;
  float4 acc = make_float4(0.f, 0.f, 0.f, 0.f);

  for (int base = 0; base < total; base += 64) {
    int idx = base + lane;
    int sidx = csr_src[beg + (idx < total ? idx : total - 1)];  // coalesced window
    const int lim = min(64, total - base);
    for (int c0 = 0; c0 < lim; c0 += 8) {
      int iA = c0 + g, iB = c0 + 4 + g;
      int sA = __shfl(sidx, iA);               // bpermute: no global dep
      int sB = __shfl(sidx, iB);               // (clamped idx -> always valid row)
      ushort4 uA = *reinterpret_cast<const ushort4*>(xlq + (size_t)sA * 64);
      ushort4 uB = *reinterpret_cast<const ushort4*>(xlq + (size_t)sB * 64);
      // chunk A
      float xA0 = bf2f(uA.x), xA1 = bf2f(uA.y), xA2 = bf2f(uA.z), xA3 = bf2f(uA.w);
      float aA0 = xA0 + xrv.x; aA0 = fmaxf(aA0, 0.2f * aA0);
      float aA1 = xA1 + xrv.y; aA1 = fmaxf(aA1, 0.2f * aA1);
      float aA2 = xA2 + xrv.z; aA2 = fmaxf(aA2, 0.2f * aA2);
      float aA3 = xA3 + xrv.w; aA3 = fmaxf(aA3, 0.2f * aA3);
      float pA = aA0 * attv.x + aA1 * attv.y + aA2 * attv.z + aA3 * attv.w;
      float vA = dpp_add<0xB1>(pA);            // head logit on pair lanes
      float exA = __expf(iA < lim ? vA : NEGB);
      den  += exA;
      acc.x += exA * xA0; acc.y += exA * xA1;
      acc.z += exA * xA2; acc.w += exA * xA3;
      // chunk B (independent)
      float xB0 = bf2f(uB.x), xB1 = bf2f(uB.y), xB2 = bf2f(uB.z), xB3 = bf2f(uB.w);
      float aB0 = xB0 + xrv.x; aB0 = fmaxf(aB0, 0.2f * aB0);
      float aB1 = xB1 + xrv.y; aB1 = fmaxf(aB1, 0.2f * aB1);
      float aB2 = xB2 + xrv.z; aB2 = fmaxf(aB2, 0.2f * aB2);
      float aB3 = xB3 + xrv.w; aB3 = fmaxf(aB3, 0.2f * aB3);
      float pB = aB0 * attv.x + aB1 * attv.y + aB2 * attv.z + aB3 * attv.w;
      float vB = dpp_add<0xB1>(pB);
      float exB = __expf(iB < lim ? vB : NEGB);
      den  += exB;
      acc.x += exB * xB0; acc.y += exB * xB1;
      acc.z += exB * xB2; acc.w += exB * xB3;
    }
  }
  // combine the 4 edge slots (pair lanes already share den)
  acc.x += __shfl_xor(acc.x, 16); acc.y += __shfl_xor(acc.y, 16);
  acc.z += __shfl_xor(acc.z, 16); acc.w += __shfl_xor(acc.w, 16);
  acc.x += __shfl_xor(acc.x, 32); acc.y += __shfl_xor(acc.y, 32);
  acc.z += __shfl_xor(acc.z, 32); acc.w += __shfl_xor(acc.w, 32);
  den += __shfl_xor(den, 16);
  den += __shfl_xor(den, 32);
  const float inv = 1.0f / (den + 1e-16f);
  const float4 bi = *reinterpret_cast<const float4*>(bias + q * 4);
  float o0 = acc.x * inv + bi.x; o0 = o0 > 0.f ? o0 : __expf(o0) - 1.0f;  // elu
  float o1 = acc.y * inv + bi.y; o1 = o1 > 0.f ? o1 : __expf(o1) - 1.0f;
  float o2 = acc.z * inv + bi.z; o2 = o2 > 0.f ? o2 : __expf(o2) - 1.0f;
  float o3 = acc.w * inv + bi.w; o3 = o3 > 0.f ? o3 : __expf(o3) - 1.0f;

  // redistribute h1 to one channel per lane (channel = lane)
  int srcl = lane >> 2;
  float c0 = __shfl(o0, srcl);
  float c1 = __shfl(o1, srcl);
  float c2 = __shfl(o2, srcl);
  float c3 = __shfl(o3, srcl);
  int r = lane & 3;
  float o = (r == 0) ? c0 : (r == 1) ? c1 : (r == 2) ? c2 : c3;

  // in-wave layer-2 transforms: out[j] = sum_l o_l * Ws2[l][j]
  const int j    = lane & 31;
  const int half = lane >> 5;              // 0: l=0..31, 1: l=32..63
  float part2 = 0.0f;
#pragma unroll 8
  for (int l = 0; l < 32; ++l) {
    int src = half * 32 + l;
    float ov = __shfl(o, src);
    part2 += ov * Ws2[src * 32 + j];
  }
  part2 += __shfl_xor(part2, 32);          // combine the two halves
  if (lane < 16)      xl2[(size_t)node * 16 + j]        = part2 + b2s[j];
  else if (lane < 32) xr2[(size_t)node * 16 + (j - 16)] = part2 + b2s[j];
}

// ---------------- Fused layer 2 (no online max; bounded-logit argument) -------
__global__ void fused_layer2(const int* __restrict__ row_start, const int* __restrict__ csr_src,
                             const float* __restrict__ xl, const float* __restrict__ xr,
                             const float* __restrict__ att, const float* __restrict__ bias,
                             float* __restrict__ out, int n) {
  int node = blockIdx.x * 16 + (threadIdx.x >> 4);
  if (node >= n) return;
  int c = threadIdx.x & 15;
  const float attv = att[c];
  const float xrv  = xr[(size_t)node * 16 + c];
  const int beg = row_start[node], end = row_start[node + 1];
  float den = 0.0f, acc = 0.0f;
  int p = beg;
  for (; p + 4 <= end; p += 4) {
    int s0 = csr_src[p + 0], s1 = csr_src[p + 1];
    int s2 = csr_src[p + 2], s3 = csr_src[p + 3];
    float x0 = xl[(size_t)s0 * 16 + c];
    float x1 = xl[(size_t)s1 * 16 + c];
    float x2 = xl[(size_t)s2 * 16 + c];
    float x3 = xl[(size_t)s3 * 16 + c];
    float a0 = x0 + xrv; a0 = a0 > 0.f ? a0 : 0.2f * a0;
    float a1 = x1 + xrv; a1 = a1 > 0.f ? a1 : 0.2f * a1;
    float a2 = x2 + xrv; a2 = a2 > 0.f ? a2 : 0.2f * a2;
    float a3 = x3 + xrv; a3 = a3 > 0.f ? a3 : 0.2f * a3;
    float e0 = __expf(sum16_dpp(a0 * attv));
    float e1 = __expf(sum16_dpp(a1 * attv));
    float e2 = __expf(sum16_dpp(a2 * attv));
    float e3 = __expf(sum16_dpp(a3 * attv));
    den += (e0 + e1) + (e2 + e3);
    acc += (e0 * x0 + e1 * x1) + (e2 * x2 + e3 * x3);
  }
  for (; p < end; ++p) {
    int s = csr_src[p];
    float xv = xl[(size_t)s * 16 + c];
    float a = xv + xrv; a = a > 0.f ? a : 0.2f * a;
    float ex = __expf(sum16_dpp(a * attv));
    den += ex;
    acc += ex * xv;
  }
  out[(size_t)node * 16 + c] = acc / (den + 1e-16f) + bias[c];   // no elu after conv2
}

// ---------------- Pooling + classifier ---------------------------------------

__global__ void pool_kernel(const float* __restrict__ h2, const int* __restrict__ batch,
                            float* __restrict__ sums, float* __restrict__ cnts, int n) {
  __shared__ float ls[NB * CH2_];
  __shared__ float lc[NB];
  for (int i = threadIdx.x; i < NB * CH2_; i += blockDim.x) ls[i] = 0.0f;
  for (int i = threadIdx.x; i < NB; i += blockDim.x) lc[i] = 0.0f;
  __syncthreads();
  int total = n * 16;
  int stride = gridDim.x * blockDim.x;
  for (int i = blockIdx.x * blockDim.x + threadIdx.x; i < total; i += stride) {
    int node = i >> 4, c = i & 15;
    int b = batch[node];
    atomicAdd(&ls[b * 16 + c], h2[i]);
    if (c == 0) atomicAdd(&lc[b], 1.0f);
  }
  __syncthreads();
  for (int i = threadIdx.x; i < NB * CH2_; i += blockDim.x)
    if (ls[i] != 0.0f) atomicAdd(&sums[i], ls[i]);
  for (int i = threadIdx.x; i < NB; i += blockDim.x)
    if (lc[i] != 0.0f) atomicAdd(&cnts[i], lc[i]);
}

__global__ void classifier(const float* __restrict__ sums, const float* __restrict__ cnts,
                           const float* __restrict__ Wc, const float* __restrict__ bc,
                           float* __restrict__ out) {
  int b = threadIdx.x;
  if (b >= NB) return;
  float cnt = cnts[b];
  cnt = cnt > 1.0f ? cnt : 1.0f;
  float acc = 0.0f;
  for (int c = 0; c < 16; ++c) {
    float p = sums[b * 16 + c] / cnt;
    out[NB + b * 16 + c] = p;   // pooled, output 1
    acc += p * Wc[c];
  }
  out[b] = acc + bc[0];         // out, output 0
}

extern "C" void kernel_launch(void* const* d_in, const int* in_sizes, int n_in,
                              void* d_out, int out_size, void* d_ws, size_t ws_size,
                              hipStream_t stream) {
  const float* x     = (const float*)d_in[0];
  const int*   ei    = (const int*)d_in[1];
  const int*   batch = (const int*)d_in[2];
  const float* Wl1   = (const float*)d_in[3];
  const float* bl1   = (const float*)d_in[4];
  const float* Wr1   = (const float*)d_in[5];
  const float* br1   = (const float*)d_in[6];
  const float* att1  = (const float*)d_in[7];
  const float* bias1 = (const float*)d_in[8];
  const float* Wl2   = (const float*)d_in[9];
  const float* bl2   = (const float*)d_in[10];
  const float* Wr2   = (const float*)d_in[11];
  const float* br2   = (const float*)d_in[12];
  const float* att2  = (const float*)d_in[13];
  const float* bias2 = (const float*)d_in[14];
  const float* Wc    = (const float*)d_in[15];
  const float* bc    = (const float*)d_in[16];
  float* out = (float*)d_out;

  const int N  = in_sizes[0] / F_IN;
  const int E  = in_sizes[1] / 2;
  const int E2 = E + N;
  const int nbuk = (N + 255) >> 8;   // 391 for N=100K (<=512 assumed)

  // Workspace layout
  float* ws   = (float*)d_ws;
  unsigned short* xl1 = (unsigned short*)ws;   // N*64 bf16
  float* xr1  = (float*)(xl1 + (size_t)N * 64);// N*64 fp32
  float* xl2  = xr1 + (size_t)N * 64;          // N*16
  float* xr2  = xl2 + (size_t)N * 16;          // N*16
  float* h2   = xr2 + (size_t)N * 16;          // N*16
  int* irow   = (int*)(h2 + (size_t)N * 16);   // N+1
  int* icsr   = irow + (N + 1);                // E2
  int* gcnt   = icsr + E2;                     // 512
  int* gbase  = gcnt + 512;                    // 512+1
  int* gbuk   = gbase + 513 + 2;               // nbuk*BUKPAD
  float* sums = (float*)(gbuk + (size_t)nbuk * BUKPAD);  // NB*16
  float* cnts = sums + NB * CH2_;              // NB

  // ---- CSR build (2-pass bucketed counting sort) ----
  fill_f32<<<1, 256, 0, stream>>>((float*)gcnt, 0.0f, 512);
  bucket_scatter<<<(E2 + 8191) / 8192, 256, 0, stream>>>(ei, E, E2, gcnt, gbuk);
  bucket_prefix<<<1, 64, 0, stream>>>(gcnt, nbuk, gbase, irow, N);
  bucket_csr<<<nbuk, 256, 0, stream>>>(gcnt, gbase, gbuk, irow, icsr, N);

  // ---- layer 1 GEMM (xl bf16, xr fp32) ----
  gemm_dual_l1<<<(N + 63) / 64, 256, 0, stream>>>(
      x, Wl1, bl1, Wr1, br1, xl1, xr1, N);

  // ---- fused layer 1 + layer-2 linear transforms ----
  fused_layer1<<<(N + 3) / 4, 256, 0, stream>>>(
      irow, icsr, xl1, xr1, att1, bias1, Wl2, bl2, Wr2, br2, xl2, xr2, N);

  // ---- fused layer 2 ----
  fused_layer2<<<(N + 15) / 16, 256, 0, stream>>>(irow, icsr, xl2, xr2, att2, bias2, h2, N);

  // ---- pooling + classifier ----
  fill_f32<<<1, 256, 0, stream>>>(sums, 0.0f, NB * CH2_ + NB);
  pool_kernel<<<256, 256, 0, stream>>>(h2, batch, sums, cnts, N);
  classifier<<<1, 64, 0, stream>>>(sums, cnts, Wc, bc, out);
}

// Round 11
// 234.488 us; speedup vs baseline: 1.2483x; 1.1297x over previous
//
#include <hip/hip_runtime.h>
#include <cstdint>
#include <cstddef>

// Problem constants (shapes fixed by the reference)
#define F_IN   128
#define HC1    64    // heads1*ch1 = 8*8
#define CH2_   16
#define NB     64    // batch graphs
#define BUKPAD 8192  // per-bucket padding (avg fill ~4350 for E=1.6M, N=100K)

typedef __attribute__((ext_vector_type(8))) short bf16x8;
typedef __attribute__((ext_vector_type(4))) float f32x4;

__global__ void fill_f32(float* __restrict__ p, float v, int n) {
  int i = blockIdx.x * blockDim.x + threadIdx.x;
  int stride = gridDim.x * blockDim.x;
  for (; i < n; i += stride) p[i] = v;
}

__device__ __forceinline__ unsigned short f2bf_rne(float v) {
  unsigned int u = __float_as_uint(v);
  unsigned int r = (u + 0x7FFFu + ((u >> 16) & 1u)) >> 16;   // round-nearest-even
  return (unsigned short)r;
}
__device__ __forceinline__ float bf2f(unsigned short b) {
  return __uint_as_float((unsigned int)b << 16);              // exact
}

// ---------------- DPP cross-lane reductions (full-rate VALU, no LDS pipe) -----
template<int CTRL>
__device__ __forceinline__ float dpp_add(float v) {
  int j = __builtin_amdgcn_update_dpp(0, __float_as_int(v), CTRL, 0xF, 0xF, true);
  return v + __int_as_float(j);
}
__device__ __forceinline__ float sum16_dpp(float v) {  // sum over each 16-lane row
  v = dpp_add<0xB1>(v);
  v = dpp_add<0x4E>(v);
  v = dpp_add<0x141>(v);
  v = dpp_add<0x140>(v);  // row_mirror
  return v;
}

// ---------------- Layer-1 GEMM on matrix cores --------------------------------
// C[N][128] = x[N][128] @ [Wl1|Wr1] via mfma_f32_16x16x32_bf16.
// Accuracy: x split into bf16 hi+lo (2 MFMAs, same fp32 acc) -> only W's bf16
// rounding remains (~0.2% rel, same order as the already-passing bf16 xl store).
// Layout safety: A and B fragments are staged with the SAME assumed lane->k
// map (k = (lane>>4)*8 + e), so any error in the k-permutation cancels (sum
// over slots == sum over k). Only the C/D layout (col=lane&15,
// row=(lane>>4)*4+reg) is a hard HW assumption [m89-verified].

// Setup: swizzle [Wl|Wr] into fragment order, bf16:
// wfrag[(((ks*8+tile)*64+lane)*8)+e] = Wcat[ks*32+(lane>>4)*8+e][tile*16+(lane&15)]
__global__ void build_wfrag(const float* __restrict__ Wl, const float* __restrict__ Wr,
                            unsigned short* __restrict__ wfrag) {
  int idx = blockIdx.x * 256 + threadIdx.x;
  if (idx >= 16384) return;
  int e    = idx & 7;
  int lane = (idx >> 3) & 63;
  int tile = (idx >> 9) & 7;
  int ks   = idx >> 12;
  int k    = ks * 32 + (lane >> 4) * 8 + e;
  int col  = tile * 16 + (lane & 15);
  float v = (col < 64) ? Wl[k * 64 + col] : Wr[k * 64 + (col - 64)];
  wfrag[idx] = f2bf_rne(v);
}

__global__ __launch_bounds__(256) void gemm_mfma_l1(
    const float* __restrict__ x, const unsigned short* __restrict__ wfrag,
    const float* __restrict__ bl, const float* __restrict__ br,
    unsigned short* __restrict__ ya, float* __restrict__ yb, int n) {
  constexpr int RP = 136;                       // row stride in bf16 (128+8 pad)
  __shared__ __align__(16) char smem[34816 + 32768];
  unsigned short* axhi = (unsigned short*)smem;             // 64*136*2 = 17408 B
  unsigned short* axlo = (unsigned short*)(smem + 17408);   // 17408 B
  unsigned short* wf   = (unsigned short*)(smem + 34816);   // 32768 B
  float* outs = (float*)smem;                  // epilogue overlay (32768 B)

  const int t = threadIdx.x;
  const int node0 = blockIdx.x * 64;

  // stage W fragments (32 KB, coalesced int4)
  for (int i = t; i < 2048; i += 256)
    reinterpret_cast<int4*>(wf)[i] = reinterpret_cast<const int4*>(wfrag)[i];
  // stage x tile as bf16 hi/lo
  for (int i = t; i < 64 * 32; i += 256) {
    int row = i >> 5, kk = (i & 31) * 4;
    int node = node0 + row;
    float4 v = make_float4(0.f, 0.f, 0.f, 0.f);
    if (node < n) v = *reinterpret_cast<const float4*>(x + (size_t)node * 128 + kk);
    ushort4 hi, lo;
    hi.x = f2bf_rne(v.x); lo.x = f2bf_rne(v.x - bf2f(hi.x));
    hi.y = f2bf_rne(v.y); lo.y = f2bf_rne(v.y - bf2f(hi.y));
    hi.z = f2bf_rne(v.z); lo.z = f2bf_rne(v.z - bf2f(hi.z));
    hi.w = f2bf_rne(v.w); lo.w = f2bf_rne(v.w - bf2f(hi.w));
    *reinterpret_cast<ushort4*>(axhi + row * RP + kk) = hi;
    *reinterpret_cast<ushort4*>(axlo + row * RP + kk) = lo;
  }
  __syncthreads();

  const int wv   = t >> 6;        // wave 0..3 -> rows wv*16..wv*16+15
  const int lane = t & 63;
  const int mrow = lane & 15;
  const int kg   = lane >> 4;
  f32x4 acc[8];
#pragma unroll
  for (int i = 0; i < 8; ++i) acc[i] = (f32x4){0.f, 0.f, 0.f, 0.f};
  const int abase = (wv * 16 + mrow) * RP;
#pragma unroll
  for (int ks = 0; ks < 4; ++ks) {
    int aoff = abase + ks * 32 + kg * 8;
    bf16x8 ahi = *reinterpret_cast<const bf16x8*>(axhi + aoff);
    bf16x8 alo = *reinterpret_cast<const bf16x8*>(axlo + aoff);
#pragma unroll
    for (int tl = 0; tl < 8; ++tl) {
      bf16x8 b = *reinterpret_cast<const bf16x8*>(wf + ((ks * 8 + tl) * 64 + lane) * 8);
      acc[tl] = __builtin_amdgcn_mfma_f32_16x16x32_bf16(alo, b, acc[tl], 0, 0, 0);
      acc[tl] = __builtin_amdgcn_mfma_f32_16x16x32_bf16(ahi, b, acc[tl], 0, 0, 0);
    }
  }
  __syncthreads();                 // A-stage dead; reuse as epilogue buffer
#pragma unroll
  for (int tl = 0; tl < 8; ++tl)
#pragma unroll
    for (int r = 0; r < 4; ++r) {
      int row = wv * 16 + kg * 4 + r;          // C/D: row=(lane>>4)*4+reg
      outs[row * 128 + tl * 16 + mrow] = acc[tl][r];
    }
  __syncthreads();
  // coalesced final stores (epilogue-through-LDS avoids partial-line write amp)
  for (int i = t; i < 64 * 64; i += 256) {
    int row = i >> 6, col = i & 63;
    int node = node0 + row;
    if (node < n) ya[(size_t)node * 64 + col] = f2bf_rne(outs[row * 128 + col] + bl[col]);
  }
  for (int i = t; i < 64 * 64; i += 256) {
    int row = i >> 6, col = i & 63;
    int node = node0 + row;
    if (node < n) yb[(size_t)node * 64 + col] = outs[row * 128 + 64 + col] + br[col];
  }
}

// ---------------- CSR build via 2-pass bucketed counting sort -----------------

__global__ void bucket_scatter(const int* __restrict__ ei, int E, int E2,
                               int* __restrict__ gcnt, int* __restrict__ gbuk) {
  __shared__ int hbase[512];
  __shared__ int hcnt[512];
  const int t = threadIdx.x;
  for (int i = t; i < 512; i += 256) { hbase[i] = 0; hcnt[i] = 0; }
  __syncthreads();
  int srcs[32], dsts[32];
  const int tile0 = blockIdx.x * 8192;
#pragma unroll
  for (int k = 0; k < 32; ++k) {
    int e = tile0 + k * 256 + t;          // coalesced
    int s = -1, d = 0;
    if (e < E2) {
      if (e < E) { s = ei[e]; d = ei[E + e]; } else { s = d = e - E; }
      atomicAdd(&hbase[d >> 8], 1);       // LDS atomic
    }
    srcs[k] = s; dsts[k] = d;
  }
  __syncthreads();
  for (int i = t; i < 512; i += 256) {    // reserve this block's run per bucket
    int c = hbase[i];
    hbase[i] = (c > 0) ? atomicAdd(&gcnt[i], c) : 0;
  }
  __syncthreads();
#pragma unroll
  for (int k = 0; k < 32; ++k) {
    if (srcs[k] >= 0) {
      int d = dsts[k], b = d >> 8;
      int r = atomicAdd(&hcnt[b], 1);     // LDS atomic: rank within (block,bucket)
      int pl = hbase[b] + r;
      if (pl < BUKPAD) gbuk[(size_t)b * BUKPAD + pl] = (srcs[k] << 8) | (d & 255);
    }
  }
}

__global__ void bucket_prefix(const int* __restrict__ gcnt, int nbuk,
                              int* __restrict__ gbase, int* __restrict__ row_start, int n) {
  int lane = threadIdx.x;  // 64 threads
  int carry = 0;
  for (int basei = 0; basei < nbuk; basei += 64) {
    int i = basei + lane;
    int orig = (i < nbuk) ? gcnt[i] : 0;
    int v = orig;
    for (int off = 1; off < 64; off <<= 1) {
      int u = __shfl_up(v, off);
      if (lane >= off) v += u;
    }
    if (i < nbuk) gbase[i] = carry + v - orig;
    carry += __shfl(v, 63);
  }
  if (lane == 0) row_start[n] = carry;    // == E2
}

__global__ void bucket_csr(const int* __restrict__ gcnt, const int* __restrict__ gbase,
                           const int* __restrict__ gbuk,
                           int* __restrict__ row_start, int* __restrict__ csr_src, int n) {
  const int b = blockIdx.x;
  const int t = threadIdx.x;
  const int node0 = b << 8;
  const int cntb = min(gcnt[b], BUKPAD);
  const int base = gbase[b];
  const int* buk = gbuk + (size_t)b * BUKPAD;
  __shared__ int h[256];
  __shared__ int off[256];
  h[t] = 0;
  __syncthreads();
  for (int i = t; i < cntb; i += 256) atomicAdd(&h[buk[i] & 255], 1);
  __syncthreads();
  off[t] = h[t];
  __syncthreads();
  for (int o = 1; o < 256; o <<= 1) {     // inclusive Hillis-Steele scan
    int u = (t >= o) ? off[t - o] : 0;
    __syncthreads();
    off[t] += u;
    __syncthreads();
  }
  int excl = off[t] - h[t];
  if (node0 + t < n) row_start[node0 + t] = base + excl;
  h[t] = excl;                            // running counter per node
  __syncthreads();
  for (int i = t; i < cntb; i += 256) {
    int p = buk[i];
    int r = atomicAdd(&h[p & 255], 1);    // LDS atomic
    csr_src[base + r] = p >> 8;           // store within ~17KB L2-hot window
  }
}

// ---------------- Fused layer 1 + layer-2 linear transforms -------------------
// (round-10 latency-optimized structure: coalesced csr window + shfl src ids
//  + 2x independent gathers in flight; bf16 xl; no online max)
__global__ void fused_layer1(const int* __restrict__ row_start, const int* __restrict__ csr_src,
                             const unsigned short* __restrict__ xl, const float* __restrict__ xr,
                             const float* __restrict__ att, const float* __restrict__ bias,
                             const float* __restrict__ Wl2, const float* __restrict__ bl2,
                             const float* __restrict__ Wr2, const float* __restrict__ br2,
                             float* __restrict__ xl2, float* __restrict__ xr2, int n) {
  __shared__ float Ws2[64 * 32];   // [l][j]: j<16 -> Wl2 col j, j>=16 -> Wr2 col j-16
  __shared__ float b2s[32];
  const int t = threadIdx.x;
  for (int i = t; i < 64 * 16; i += 256) {
    int l = i >> 4, j = i & 15;
    Ws2[l * 32 + j]      = Wl2[i];
    Ws2[l * 32 + 16 + j] = Wr2[i];
  }
  if (t < 16) { b2s[t] = bl2[t]; b2s[16 + t] = br2[t]; }
  __syncthreads();

  const int node = blockIdx.x * 4 + (t >> 6);
  if (node >= n) return;
  const int lane = t & 63;
  const int g = lane >> 4;            // edge slot 0..3 within a chunk
  const int q = lane & 15;            // channels 4q..4q+3, head q>>1
  const float4 attv = *reinterpret_cast<const float4*>(att + q * 4);
  const float4 xrv  = *reinterpret_cast<const float4*>(xr + (size_t)node * 64 + q * 4);
  const unsigned short* xlq = xl + q * 4;
  const int beg = row_start[node];
  const int total = row_start[node + 1] - beg;   // >= 1 (self loop)
  const float NEGB = -3.0e38f;                   // masked slots: exp -> 0
  float den = 0.0f;
  float4 acc = make_float4(0.f, 0.f, 0.f, 0.f);

  for (int base = 0; base < total; base += 64) {
    int idx = base + lane;
    int sidx = csr_src[beg + (idx < total ? idx : total - 1)];  // coalesced window
    const int lim = min(64, total - base);
    for (int c0 = 0; c0 < lim; c0 += 8) {
      int iA = c0 + g, iB = c0 + 4 + g;
      int sA = __shfl(sidx, iA);               // bpermute: no global dep
      int sB = __shfl(sidx, iB);               // (clamped idx -> always valid row)
      ushort4 uA = *reinterpret_cast<const ushort4*>(xlq + (size_t)sA * 64);
      ushort4 uB = *reinterpret_cast<const ushort4*>(xlq + (size_t)sB * 64);
      // chunk A
      float xA0 = bf2f(uA.x), xA1 = bf2f(uA.y), xA2 = bf2f(uA.z), xA3 = bf2f(uA.w);
      float aA0 = xA0 + xrv.x; aA0 = fmaxf(aA0, 0.2f * aA0);
      float aA1 = xA1 + xrv.y; aA1 = fmaxf(aA1, 0.2f * aA1);
      float aA2 = xA2 + xrv.z; aA2 = fmaxf(aA2, 0.2f * aA2);
      float aA3 = xA3 + xrv.w; aA3 = fmaxf(aA3, 0.2f * aA3);
      float pA = aA0 * attv.x + aA1 * attv.y + aA2 * attv.z + aA3 * attv.w;
      float vA = dpp_add<0xB1>(pA);            // head logit on pair lanes
      float exA = __expf(iA < lim ? vA : NEGB);
      den  += exA;
      acc.x += exA * xA0; acc.y += exA * xA1;
      acc.z += exA * xA2; acc.w += exA * xA3;
      // chunk B (independent)
      float xB0 = bf2f(uB.x), xB1 = bf2f(uB.y), xB2 = bf2f(uB.z), xB3 = bf2f(uB.w);
      float aB0 = xB0 + xrv.x; aB0 = fmaxf(aB0, 0.2f * aB0);
      float aB1 = xB1 + xrv.y; aB1 = fmaxf(aB1, 0.2f * aB1);
      float aB2 = xB2 + xrv.z; aB2 = fmaxf(aB2, 0.2f * aB2);
      float aB3 = xB3 + xrv.w; aB3 = fmaxf(aB3, 0.2f * aB3);
      float pB = aB0 * attv.x + aB1 * attv.y + aB2 * attv.z + aB3 * attv.w;
      float vB = dpp_add<0xB1>(pB);
      float exB = __expf(iB < lim ? vB : NEGB);
      den  += exB;
      acc.x += exB * xB0; acc.y += exB * xB1;
      acc.z += exB * xB2; acc.w += exB * xB3;
    }
  }
  // combine the 4 edge slots (pair lanes already share den)
  acc.x += __shfl_xor(acc.x, 16); acc.y += __shfl_xor(acc.y, 16);
  acc.z += __shfl_xor(acc.z, 16); acc.w += __shfl_xor(acc.w, 16);
  acc.x += __shfl_xor(acc.x, 32); acc.y += __shfl_xor(acc.y, 32);
  acc.z += __shfl_xor(acc.z, 32); acc.w += __shfl_xor(acc.w, 32);
  den += __shfl_xor(den, 16);
  den += __shfl_xor(den, 32);
  const float inv = 1.0f / (den + 1e-16f);
  const float4 bi = *reinterpret_cast<const float4*>(bias + q * 4);
  float o0 = acc.x * inv + bi.x; o0 = o0 > 0.f ? o0 : __expf(o0) - 1.0f;  // elu
  float o1 = acc.y * inv + bi.y; o1 = o1 > 0.f ? o1 : __expf(o1) - 1.0f;
  float o2 = acc.z * inv + bi.z; o2 = o2 > 0.f ? o2 : __expf(o2) - 1.0f;
  float o3 = acc.w * inv + bi.w; o3 = o3 > 0.f ? o3 : __expf(o3) - 1.0f;

  // redistribute h1 to one channel per lane (channel = lane)
  int srcl = lane >> 2;
  float c0 = __shfl(o0, srcl);
  float c1 = __shfl(o1, srcl);
  float c2 = __shfl(o2, srcl);
  float c3 = __shfl(o3, srcl);
  int r = lane & 3;
  float o = (r == 0) ? c0 : (r == 1) ? c1 : (r == 2) ? c2 : c3;

  // in-wave layer-2 transforms: out[j] = sum_l o_l * Ws2[l][j]
  const int j    = lane & 31;
  const int half = lane >> 5;              // 0: l=0..31, 1: l=32..63
  float part2 = 0.0f;
#pragma unroll 8
  for (int l = 0; l < 32; ++l) {
    int src = half * 32 + l;
    float ov = __shfl(o, src);
    part2 += ov * Ws2[src * 32 + j];
  }
  part2 += __shfl_xor(part2, 32);          // combine the two halves
  if (lane < 16)      xl2[(size_t)node * 16 + j]        = part2 + b2s[j];
  else if (lane < 32) xr2[(size_t)node * 16 + (j - 16)] = part2 + b2s[j];
}

// ---------------- Fused layer 2 (no online max; bounded-logit argument) -------
__global__ void fused_layer2(const int* __restrict__ row_start, const int* __restrict__ csr_src,
                             const float* __restrict__ xl, const float* __restrict__ xr,
                             const float* __restrict__ att, const float* __restrict__ bias,
                             float* __restrict__ out, int n) {
  int node = blockIdx.x * 16 + (threadIdx.x >> 4);
  if (node >= n) return;
  int c = threadIdx.x & 15;
  const float attv = att[c];
  const float xrv  = xr[(size_t)node * 16 + c];
  const int beg = row_start[node], end = row_start[node + 1];
  float den = 0.0f, acc = 0.0f;
  int p = beg;
  for (; p + 4 <= end; p += 4) {
    int s0 = csr_src[p + 0], s1 = csr_src[p + 1];
    int s2 = csr_src[p + 2], s3 = csr_src[p + 3];
    float x0 = xl[(size_t)s0 * 16 + c];
    float x1 = xl[(size_t)s1 * 16 + c];
    float x2 = xl[(size_t)s2 * 16 + c];
    float x3 = xl[(size_t)s3 * 16 + c];
    float a0 = x0 + xrv; a0 = a0 > 0.f ? a0 : 0.2f * a0;
    float a1 = x1 + xrv; a1 = a1 > 0.f ? a1 : 0.2f * a1;
    float a2 = x2 + xrv; a2 = a2 > 0.f ? a2 : 0.2f * a2;
    float a3 = x3 + xrv; a3 = a3 > 0.f ? a3 : 0.2f * a3;
    float e0 = __expf(sum16_dpp(a0 * attv));
    float e1 = __expf(sum16_dpp(a1 * attv));
    float e2 = __expf(sum16_dpp(a2 * attv));
    float e3 = __expf(sum16_dpp(a3 * attv));
    den += (e0 + e1) + (e2 + e3);
    acc += (e0 * x0 + e1 * x1) + (e2 * x2 + e3 * x3);
  }
  for (; p < end; ++p) {
    int s = csr_src[p];
    float xv = xl[(size_t)s * 16 + c];
    float a = xv + xrv; a = a > 0.f ? a : 0.2f * a;
    float ex = __expf(sum16_dpp(a * attv));
    den += ex;
    acc += ex * xv;
  }
  out[(size_t)node * 16 + c] = acc / (den + 1e-16f) + bias[c];   // no elu after conv2
}

// ---------------- Pooling + classifier ---------------------------------------

__global__ void pool_kernel(const float* __restrict__ h2, const int* __restrict__ batch,
                            float* __restrict__ sums, float* __restrict__ cnts, int n) {
  __shared__ float ls[NB * CH2_];
  __shared__ float lc[NB];
  for (int i = threadIdx.x; i < NB * CH2_; i += blockDim.x) ls[i] = 0.0f;
  for (int i = threadIdx.x; i < NB; i += blockDim.x) lc[i] = 0.0f;
  __syncthreads();
  int total = n * 16;
  int stride = gridDim.x * blockDim.x;
  for (int i = blockIdx.x * blockDim.x + threadIdx.x; i < total; i += stride) {
    int node = i >> 4, c = i & 15;
    int b = batch[node];
    atomicAdd(&ls[b * 16 + c], h2[i]);
    if (c == 0) atomicAdd(&lc[b], 1.0f);
  }
  __syncthreads();
  for (int i = threadIdx.x; i < NB * CH2_; i += blockDim.x)
    if (ls[i] != 0.0f) atomicAdd(&sums[i], ls[i]);
  for (int i = threadIdx.x; i < NB; i += blockDim.x)
    if (lc[i] != 0.0f) atomicAdd(&cnts[i], lc[i]);
}

__global__ void classifier(const float* __restrict__ sums, const float* __restrict__ cnts,
                           const float* __restrict__ Wc, const float* __restrict__ bc,
                           float* __restrict__ out) {
  int b = threadIdx.x;
  if (b >= NB) return;
  float cnt = cnts[b];
  cnt = cnt > 1.0f ? cnt : 1.0f;
  float acc = 0.0f;
  for (int c = 0; c < 16; ++c) {
    float p = sums[b * 16 + c] / cnt;
    out[NB + b * 16 + c] = p;   // pooled, output 1
    acc += p * Wc[c];
  }
  out[b] = acc + bc[0];         // out, output 0
}

extern "C" void kernel_launch(void* const* d_in, const int* in_sizes, int n_in,
                              void* d_out, int out_size, void* d_ws, size_t ws_size,
                              hipStream_t stream) {
  const float* x     = (const float*)d_in[0];
  const int*   ei    = (const int*)d_in[1];
  const int*   batch = (const int*)d_in[2];
  const float* Wl1   = (const float*)d_in[3];
  const float* bl1   = (const float*)d_in[4];
  const float* Wr1   = (const float*)d_in[5];
  const float* br1   = (const float*)d_in[6];
  const float* att1  = (const float*)d_in[7];
  const float* bias1 = (const float*)d_in[8];
  const float* Wl2   = (const float*)d_in[9];
  const float* bl2   = (const float*)d_in[10];
  const float* Wr2   = (const float*)d_in[11];
  const float* br2   = (const float*)d_in[12];
  const float* att2  = (const float*)d_in[13];
  const float* bias2 = (const float*)d_in[14];
  const float* Wc    = (const float*)d_in[15];
  const float* bc    = (const float*)d_in[16];
  float* out = (float*)d_out;

  const int N  = in_sizes[0] / F_IN;
  const int E  = in_sizes[1] / 2;
  const int E2 = E + N;
  const int nbuk = (N + 255) >> 8;   // 391 for N=100K (<=512 assumed)

  // Workspace layout
  float* ws   = (float*)d_ws;
  unsigned short* xl1 = (unsigned short*)ws;   // N*64 bf16
  float* xr1  = (float*)(xl1 + (size_t)N * 64);// N*64 fp32
  float* xl2  = xr1 + (size_t)N * 64;          // N*16
  float* xr2  = xl2 + (size_t)N * 16;          // N*16
  float* h2   = xr2 + (size_t)N * 16;          // N*16
  int* irow   = (int*)(h2 + (size_t)N * 16);   // N+1
  int* icsr   = irow + (N + 1);                // E2
  int* gcnt   = icsr + E2;                     // 512
  int* gbase  = gcnt + 512;                    // 512+1
  int* gbuk   = gbase + 513 + 2;               // nbuk*BUKPAD
  unsigned short* wfrag =
      (unsigned short*)(((uintptr_t)(gbuk + (size_t)nbuk * BUKPAD) + 15) & ~(uintptr_t)15);
  float* sums = (float*)(wfrag + 16384);       // NB*16
  float* cnts = sums + NB * CH2_;              // NB

  // ---- CSR build (2-pass bucketed counting sort) ----
  fill_f32<<<1, 256, 0, stream>>>((float*)gcnt, 0.0f, 512);
  bucket_scatter<<<(E2 + 8191) / 8192, 256, 0, stream>>>(ei, E, E2, gcnt, gbuk);
  bucket_prefix<<<1, 64, 0, stream>>>(gcnt, nbuk, gbase, irow, N);
  bucket_csr<<<nbuk, 256, 0, stream>>>(gcnt, gbase, gbuk, irow, icsr, N);

  // ---- layer 1 GEMM on matrix cores (xl bf16, xr fp32) ----
  build_wfrag<<<64, 256, 0, stream>>>(Wl1, Wr1, wfrag);
  gemm_mfma_l1<<<(N + 63) / 64, 256, 0, stream>>>(x, wfrag, bl1, br1, xl1, xr1, N);

  // ---- fused layer 1 + layer-2 linear transforms ----
  fused_layer1<<<(N + 3) / 4, 256, 0, stream>>>(
      irow, icsr, xl1, xr1, att1, bias1, Wl2, bl2, Wr2, br2, xl2, xr2, N);

  // ---- fused layer 2 ----
  fused_layer2<<<(N + 15) / 16, 256, 0, stream>>>(irow, icsr, xl2, xr2, att2, bias2, h2, N);

  // ---- pooling + classifier ----
  fill_f32<<<1, 256, 0, stream>>>(sums, 0.0f, NB * CH2_ + NB);
  pool_kernel<<<256, 256, 0, stream>>>(h2, batch, sums, cnts, N);
  classifier<<<1, 64, 0, stream>>>(sums, cnts, Wc, bc, out);
}

// Round 12
// 226.643 us; speedup vs baseline: 1.2915x; 1.0346x over previous
//
#include <hip/hip_runtime.h>
#include <cstdint>
#include <cstddef>

// Problem constants (shapes fixed by the reference)
#define F_IN   128
#define HC1    64    // heads1*ch1 = 8*8
#define CH2_   16
#define NB     64    // batch graphs
#define BUKPAD 8192  // per-bucket padding (avg fill ~4350 for E=1.6M, N=100K)

typedef __attribute__((ext_vector_type(8))) short bf16x8;
typedef __attribute__((ext_vector_type(4))) float f32x4;

__global__ void fill_f32(float* __restrict__ p, float v, int n) {
  int i = blockIdx.x * blockDim.x + threadIdx.x;
  int stride = gridDim.x * blockDim.x;
  for (; i < n; i += stride) p[i] = v;
}

__device__ __forceinline__ unsigned short f2bf_rne(float v) {
  unsigned int u = __float_as_uint(v);
  unsigned int r = (u + 0x7FFFu + ((u >> 16) & 1u)) >> 16;   // round-nearest-even
  return (unsigned short)r;
}
__device__ __forceinline__ float bf2f(unsigned short b) {
  return __uint_as_float((unsigned int)b << 16);              // exact
}

// ---------------- DPP cross-lane reductions (full-rate VALU, no LDS pipe) -----
template<int CTRL>
__device__ __forceinline__ float dpp_add(float v) {
  int j = __builtin_amdgcn_update_dpp(0, __float_as_int(v), CTRL, 0xF, 0xF, true);
  return v + __int_as_float(j);
}
__device__ __forceinline__ float sum16_dpp(float v) {  // sum over each 16-lane row
  v = dpp_add<0xB1>(v);
  v = dpp_add<0x4E>(v);
  v = dpp_add<0x141>(v);
  v = dpp_add<0x140>(v);  // row_mirror
  return v;
}

// ---------------- Layer-1 GEMM on matrix cores (round-11, unchanged) ----------
__global__ void build_wfrag(const float* __restrict__ Wl, const float* __restrict__ Wr,
                            unsigned short* __restrict__ wfrag) {
  int idx = blockIdx.x * 256 + threadIdx.x;
  if (idx >= 16384) return;
  int e    = idx & 7;
  int lane = (idx >> 3) & 63;
  int tile = (idx >> 9) & 7;
  int ks   = idx >> 12;
  int k    = ks * 32 + (lane >> 4) * 8 + e;
  int col  = tile * 16 + (lane & 15);
  float v = (col < 64) ? Wl[k * 64 + col] : Wr[k * 64 + (col - 64)];
  wfrag[idx] = f2bf_rne(v);
}

__global__ __launch_bounds__(256) void gemm_mfma_l1(
    const float* __restrict__ x, const unsigned short* __restrict__ wfrag,
    const float* __restrict__ bl, const float* __restrict__ br,
    unsigned short* __restrict__ ya, float* __restrict__ yb, int n) {
  constexpr int RP = 136;                       // row stride in bf16 (128+8 pad)
  __shared__ __align__(16) char smem[34816 + 32768];
  unsigned short* axhi = (unsigned short*)smem;             // 17408 B
  unsigned short* axlo = (unsigned short*)(smem + 17408);   // 17408 B
  unsigned short* wf   = (unsigned short*)(smem + 34816);   // 32768 B
  float* outs = (float*)smem;                  // epilogue overlay

  const int t = threadIdx.x;
  const int node0 = blockIdx.x * 64;

  for (int i = t; i < 2048; i += 256)
    reinterpret_cast<int4*>(wf)[i] = reinterpret_cast<const int4*>(wfrag)[i];
  for (int i = t; i < 64 * 32; i += 256) {
    int row = i >> 5, kk = (i & 31) * 4;
    int node = node0 + row;
    float4 v = make_float4(0.f, 0.f, 0.f, 0.f);
    if (node < n) v = *reinterpret_cast<const float4*>(x + (size_t)node * 128 + kk);
    ushort4 hi, lo;
    hi.x = f2bf_rne(v.x); lo.x = f2bf_rne(v.x - bf2f(hi.x));
    hi.y = f2bf_rne(v.y); lo.y = f2bf_rne(v.y - bf2f(hi.y));
    hi.z = f2bf_rne(v.z); lo.z = f2bf_rne(v.z - bf2f(hi.z));
    hi.w = f2bf_rne(v.w); lo.w = f2bf_rne(v.w - bf2f(hi.w));
    *reinterpret_cast<ushort4*>(axhi + row * RP + kk) = hi;
    *reinterpret_cast<ushort4*>(axlo + row * RP + kk) = lo;
  }
  __syncthreads();

  const int wv   = t >> 6;
  const int lane = t & 63;
  const int mrow = lane & 15;
  const int kg   = lane >> 4;
  f32x4 acc[8];
#pragma unroll
  for (int i = 0; i < 8; ++i) acc[i] = (f32x4){0.f, 0.f, 0.f, 0.f};
  const int abase = (wv * 16 + mrow) * RP;
#pragma unroll
  for (int ks = 0; ks < 4; ++ks) {
    int aoff = abase + ks * 32 + kg * 8;
    bf16x8 ahi = *reinterpret_cast<const bf16x8*>(axhi + aoff);
    bf16x8 alo = *reinterpret_cast<const bf16x8*>(axlo + aoff);
#pragma unroll
    for (int tl = 0; tl < 8; ++tl) {
      bf16x8 b = *reinterpret_cast<const bf16x8*>(wf + ((ks * 8 + tl) * 64 + lane) * 8);
      acc[tl] = __builtin_amdgcn_mfma_f32_16x16x32_bf16(alo, b, acc[tl], 0, 0, 0);
      acc[tl] = __builtin_amdgcn_mfma_f32_16x16x32_bf16(ahi, b, acc[tl], 0, 0, 0);
    }
  }
  __syncthreads();
#pragma unroll
  for (int tl = 0; tl < 8; ++tl)
#pragma unroll
    for (int r = 0; r < 4; ++r) {
      int row = wv * 16 + kg * 4 + r;
      outs[row * 128 + tl * 16 + mrow] = acc[tl][r];
    }
  __syncthreads();
  for (int i = t; i < 64 * 64; i += 256) {
    int row = i >> 6, col = i & 63;
    int node = node0 + row;
    if (node < n) ya[(size_t)node * 64 + col] = f2bf_rne(outs[row * 128 + col] + bl[col]);
  }
  for (int i = t; i < 64 * 64; i += 256) {
    int row = i >> 6, col = i & 63;
    int node = node0 + row;
    if (node < n) yb[(size_t)node * 64 + col] = outs[row * 128 + 64 + col] + br[col];
  }
}

// ---------------- CSR build via 2-pass bucketed counting sort -----------------

__global__ void bucket_scatter(const int* __restrict__ ei, int E, int E2,
                               int* __restrict__ gcnt, int* __restrict__ gbuk) {
  __shared__ int hbase[512];
  __shared__ int hcnt[512];
  const int t = threadIdx.x;
  for (int i = t; i < 512; i += 256) { hbase[i] = 0; hcnt[i] = 0; }
  __syncthreads();
  int srcs[32], dsts[32];
  const int tile0 = blockIdx.x * 8192;
#pragma unroll
  for (int k = 0; k < 32; ++k) {
    int e = tile0 + k * 256 + t;          // coalesced
    int s = -1, d = 0;
    if (e < E2) {
      if (e < E) { s = ei[e]; d = ei[E + e]; } else { s = d = e - E; }
      atomicAdd(&hbase[d >> 8], 1);       // LDS atomic
    }
    srcs[k] = s; dsts[k] = d;
  }
  __syncthreads();
  for (int i = t; i < 512; i += 256) {
    int c = hbase[i];
    hbase[i] = (c > 0) ? atomicAdd(&gcnt[i], c) : 0;
  }
  __syncthreads();
#pragma unroll
  for (int k = 0; k < 32; ++k) {
    if (srcs[k] >= 0) {
      int d = dsts[k], b = d >> 8;
      int r = atomicAdd(&hcnt[b], 1);
      int pl = hbase[b] + r;
      if (pl < BUKPAD) gbuk[(size_t)b * BUKPAD + pl] = (srcs[k] << 8) | (d & 255);
    }
  }
}

__global__ void bucket_prefix(const int* __restrict__ gcnt, int nbuk,
                              int* __restrict__ gbase, int* __restrict__ row_start, int n) {
  int lane = threadIdx.x;  // 64 threads
  int carry = 0;
  for (int basei = 0; basei < nbuk; basei += 64) {
    int i = basei + lane;
    int orig = (i < nbuk) ? gcnt[i] : 0;
    int v = orig;
    for (int off = 1; off < 64; off <<= 1) {
      int u = __shfl_up(v, off);
      if (lane >= off) v += u;
    }
    if (i < nbuk) gbase[i] = carry + v - orig;
    carry += __shfl(v, 63);
  }
  if (lane == 0) row_start[n] = carry;    // == E2
}

__global__ void bucket_csr(const int* __restrict__ gcnt, const int* __restrict__ gbase,
                           const int* __restrict__ gbuk,
                           int* __restrict__ row_start, int* __restrict__ csr_src, int n) {
  const int b = blockIdx.x;
  const int t = threadIdx.x;
  const int node0 = b << 8;
  const int cntb = min(gcnt[b], BUKPAD);
  const int base = gbase[b];
  const int* buk = gbuk + (size_t)b * BUKPAD;
  __shared__ int h[256];
  __shared__ int off[256];
  h[t] = 0;
  __syncthreads();
  for (int i = t; i < cntb; i += 256) atomicAdd(&h[buk[i] & 255], 1);
  __syncthreads();
  off[t] = h[t];
  __syncthreads();
  for (int o = 1; o < 256; o <<= 1) {
    int u = (t >= o) ? off[t - o] : 0;
    __syncthreads();
    off[t] += u;
    __syncthreads();
  }
  int excl = off[t] - h[t];
  if (node0 + t < n) row_start[node0 + t] = base + excl;
  h[t] = excl;
  __syncthreads();
  for (int i = t; i < cntb; i += 256) {
    int p = buk[i];
    int r = atomicAdd(&h[p & 255], 1);
    csr_src[base + r] = p >> 8;
  }
}

// ---------------- Fused layer 1 + layer-2 linear transforms -------------------
// Round-12: 4 independent chunks (16 edges) in flight per iteration (round-10's
// 2-chunk unroll gave 113->93; latency-bound with FETCH served mostly by L3).
__global__ void fused_layer1(const int* __restrict__ row_start, const int* __restrict__ csr_src,
                             const unsigned short* __restrict__ xl, const float* __restrict__ xr,
                             const float* __restrict__ att, const float* __restrict__ bias,
                             const float* __restrict__ Wl2, const float* __restrict__ bl2,
                             const float* __restrict__ Wr2, const float* __restrict__ br2,
                             float* __restrict__ xl2, float* __restrict__ xr2, int n) {
  __shared__ float Ws2[64 * 32];   // [l][j]: j<16 -> Wl2 col j, j>=16 -> Wr2 col j-16
  __shared__ float b2s[32];
  const int t = threadIdx.x;
  for (int i = t; i < 64 * 16; i += 256) {
    int l = i >> 4, j = i & 15;
    Ws2[l * 32 + j]      = Wl2[i];
    Ws2[l * 32 + 16 + j] = Wr2[i];
  }
  if (t < 16) { b2s[t] = bl2[t]; b2s[16 + t] = br2[t]; }
  __syncthreads();

  const int node = blockIdx.x * 4 + (t >> 6);
  if (node >= n) return;
  const int lane = t & 63;
  const int g = lane >> 4;            // edge slot 0..3 within a chunk
  const int q = lane & 15;            // channels 4q..4q+3, head q>>1
  const float4 attv = *reinterpret_cast<const float4*>(att + q * 4);
  const float4 xrv  = *reinterpret_cast<const float4*>(xr + (size_t)node * 64 + q * 4);
  const unsigned short* xlq = xl + q * 4;
  const int beg = row_start[node];
  const int total = row_start[node + 1] - beg;   // >= 1 (self loop)
  const float NEGB = -3.0e38f;                   // masked slots: exp -> 0
  float den = 0.0f;
  float4 acc = make_float4(0.f, 0.f, 0.f, 0.f);

  for (int base = 0; base < total; base += 64) {
    int idx = base + lane;
    int sidx = csr_src[beg + (idx < total ? idx : total - 1)];  // coalesced window
    const int lim = min(64, total - base);
    for (int c0 = 0; c0 < lim; c0 += 16) {
      int ii[4]; int sv[4]; ushort4 u[4];
#pragma unroll
      for (int j = 0; j < 4; ++j) ii[j] = c0 + j * 4 + g;
#pragma unroll
      for (int j = 0; j < 4; ++j) sv[j] = __shfl(sidx, ii[j]);  // bpermute, no mem dep
#pragma unroll
      for (int j = 0; j < 4; ++j)                              // 4 gathers in flight
        u[j] = *reinterpret_cast<const ushort4*>(xlq + (size_t)sv[j] * 64);
#pragma unroll
      for (int j = 0; j < 4; ++j) {
        float x0 = bf2f(u[j].x), x1 = bf2f(u[j].y), x2 = bf2f(u[j].z), x3 = bf2f(u[j].w);
        float a0 = x0 + xrv.x; a0 = fmaxf(a0, 0.2f * a0);
        float a1 = x1 + xrv.y; a1 = fmaxf(a1, 0.2f * a1);
        float a2 = x2 + xrv.z; a2 = fmaxf(a2, 0.2f * a2);
        float a3 = x3 + xrv.w; a3 = fmaxf(a3, 0.2f * a3);
        float p = a0 * attv.x + a1 * attv.y + a2 * attv.z + a3 * attv.w;
        float v = dpp_add<0xB1>(p);              // head logit on pair lanes
        float ex = __expf(ii[j] < lim ? v : NEGB);
        den  += ex;
        acc.x += ex * x0; acc.y += ex * x1;
        acc.z += ex * x2; acc.w += ex * x3;
      }
    }
  }
  // combine the 4 edge slots (pair lanes already share den)
  acc.x += __shfl_xor(acc.x, 16); acc.y += __shfl_xor(acc.y, 16);
  acc.z += __shfl_xor(acc.z, 16); acc.w += __shfl_xor(acc.w, 16);
  acc.x += __shfl_xor(acc.x, 32); acc.y += __shfl_xor(acc.y, 32);
  acc.z += __shfl_xor(acc.z, 32); acc.w += __shfl_xor(acc.w, 32);
  den += __shfl_xor(den, 16);
  den += __shfl_xor(den, 32);
  const float inv = 1.0f / (den + 1e-16f);
  const float4 bi = *reinterpret_cast<const float4*>(bias + q * 4);
  float o0 = acc.x * inv + bi.x; o0 = o0 > 0.f ? o0 : __expf(o0) - 1.0f;  // elu
  float o1 = acc.y * inv + bi.y; o1 = o1 > 0.f ? o1 : __expf(o1) - 1.0f;
  float o2 = acc.z * inv + bi.z; o2 = o2 > 0.f ? o2 : __expf(o2) - 1.0f;
  float o3 = acc.w * inv + bi.w; o3 = o3 > 0.f ? o3 : __expf(o3) - 1.0f;

  // redistribute h1 to one channel per lane (channel = lane)
  int srcl = lane >> 2;
  float c0v = __shfl(o0, srcl);
  float c1v = __shfl(o1, srcl);
  float c2v = __shfl(o2, srcl);
  float c3v = __shfl(o3, srcl);
  int r = lane & 3;
  float o = (r == 0) ? c0v : (r == 1) ? c1v : (r == 2) ? c2v : c3v;

  // in-wave layer-2 transforms: out[j] = sum_l o_l * Ws2[l][j]
  const int j    = lane & 31;
  const int half = lane >> 5;              // 0: l=0..31, 1: l=32..63
  float part2 = 0.0f;
#pragma unroll 8
  for (int l = 0; l < 32; ++l) {
    int src = half * 32 + l;
    float ov = __shfl(o, src);
    part2 += ov * Ws2[src * 32 + j];
  }
  part2 += __shfl_xor(part2, 32);          // combine the two halves
  if (lane < 16)      xl2[(size_t)node * 16 + j]        = part2 + b2s[j];
  else if (lane < 32) xr2[(size_t)node * 16 + (j - 16)] = part2 + b2s[j];
}

// ---------------- Fused layer 2: window preload + shfl src ids ---------------
// Round-12: removes the dependent csr_src scalar loads and the divergent tail
// loop (round-10's trick, now applied here). 4 gathers in flight; tail masked
// via clamp + exp(NEGB)=0.
__global__ void fused_layer2(const int* __restrict__ row_start, const int* __restrict__ csr_src,
                             const float* __restrict__ xl, const float* __restrict__ xr,
                             const float* __restrict__ att, const float* __restrict__ bias,
                             float* __restrict__ out, int n) {
  int node = blockIdx.x * 16 + (threadIdx.x >> 4);
  if (node >= n) return;
  const int lane = threadIdx.x & 63;
  const int c = lane & 15;
  const int gbase = lane & 48;             // base lane of this node's 16-lane group
  const float attv = att[c];
  const float xrv  = xr[(size_t)node * 16 + c];
  const int beg = row_start[node];
  const int total = row_start[node + 1] - beg;   // >= 1
  const float NEGB = -3.0e38f;
  float den = 0.0f, acc = 0.0f;

  for (int base = 0; base < total; base += 16) {
    int wi = base + c;
    int sidx = csr_src[beg + (wi < total ? wi : total - 1)];   // coalesced window
    const int lim = min(16, total - base);
    for (int c0 = 0; c0 < lim; c0 += 4) {
      int sv[4]; float xv[4];
#pragma unroll
      for (int j = 0; j < 4; ++j) sv[j] = __shfl(sidx, gbase + c0 + j);
#pragma unroll
      for (int j = 0; j < 4; ++j)                 // 4 gathers in flight
        xv[j] = xl[(size_t)sv[j] * 16 + c];
#pragma unroll
      for (int j = 0; j < 4; ++j) {
        float a = xv[j] + xrv; a = fmaxf(a, 0.2f * a);
        float v = sum16_dpp(a * attv);
        float ex = __expf((c0 + j) < lim ? v : NEGB);
        den += ex;
        acc += ex * xv[j];
      }
    }
  }
  out[(size_t)node * 16 + c] = acc / (den + 1e-16f) + bias[c];   // no elu after conv2
}

// ---------------- Pooling + classifier ---------------------------------------

__global__ void pool_kernel(const float* __restrict__ h2, const int* __restrict__ batch,
                            float* __restrict__ sums, float* __restrict__ cnts, int n) {
  __shared__ float ls[NB * CH2_];
  __shared__ float lc[NB];
  for (int i = threadIdx.x; i < NB * CH2_; i += blockDim.x) ls[i] = 0.0f;
  for (int i = threadIdx.x; i < NB; i += blockDim.x) lc[i] = 0.0f;
  __syncthreads();
  int total = n * 16;
  int stride = gridDim.x * blockDim.x;
  for (int i = blockIdx.x * blockDim.x + threadIdx.x; i < total; i += stride) {
    int node = i >> 4, c = i & 15;
    int b = batch[node];
    atomicAdd(&ls[b * 16 + c], h2[i]);
    if (c == 0) atomicAdd(&lc[b], 1.0f);
  }
  __syncthreads();
  for (int i = threadIdx.x; i < NB * CH2_; i += blockDim.x)
    if (ls[i] != 0.0f) atomicAdd(&sums[i], ls[i]);
  for (int i = threadIdx.x; i < NB; i += blockDim.x)
    if (lc[i] != 0.0f) atomicAdd(&cnts[i], lc[i]);
}

__global__ void classifier(const float* __restrict__ sums, const float* __restrict__ cnts,
                           const float* __restrict__ Wc, const float* __restrict__ bc,
                           float* __restrict__ out) {
  int b = threadIdx.x;
  if (b >= NB) return;
  float cnt = cnts[b];
  cnt = cnt > 1.0f ? cnt : 1.0f;
  float acc = 0.0f;
  for (int c = 0; c < 16; ++c) {
    float p = sums[b * 16 + c] / cnt;
    out[NB + b * 16 + c] = p;   // pooled, output 1
    acc += p * Wc[c];
  }
  out[b] = acc + bc[0];         // out, output 0
}

extern "C" void kernel_launch(void* const* d_in, const int* in_sizes, int n_in,
                              void* d_out, int out_size, void* d_ws, size_t ws_size,
                              hipStream_t stream) {
  const float* x     = (const float*)d_in[0];
  const int*   ei    = (const int*)d_in[1];
  const int*   batch = (const int*)d_in[2];
  const float* Wl1   = (const float*)d_in[3];
  const float* bl1   = (const float*)d_in[4];
  const float* Wr1   = (const float*)d_in[5];
  const float* br1   = (const float*)d_in[6];
  const float* att1  = (const float*)d_in[7];
  const float* bias1 = (const float*)d_in[8];
  const float* Wl2   = (const float*)d_in[9];
  const float* bl2   = (const float*)d_in[10];
  const float* Wr2   = (const float*)d_in[11];
  const float* br2   = (const float*)d_in[12];
  const float* att2  = (const float*)d_in[13];
  const float* bias2 = (const float*)d_in[14];
  const float* Wc    = (const float*)d_in[15];
  const float* bc    = (const float*)d_in[16];
  float* out = (float*)d_out;

  const int N  = in_sizes[0] / F_IN;
  const int E  = in_sizes[1] / 2;
  const int E2 = E + N;
  const int nbuk = (N + 255) >> 8;   // 391 for N=100K (<=512 assumed)

  // Workspace layout
  float* ws   = (float*)d_ws;
  unsigned short* xl1 = (unsigned short*)ws;   // N*64 bf16
  float* xr1  = (float*)(xl1 + (size_t)N * 64);// N*64 fp32
  float* xl2  = xr1 + (size_t)N * 64;          // N*16
  float* xr2  = xl2 + (size_t)N * 16;          // N*16
  float* h2   = xr2 + (size_t)N * 16;          // N*16
  int* irow   = (int*)(h2 + (size_t)N * 16);   // N+1
  int* icsr   = irow + (N + 1);                // E2
  int* gcnt   = icsr + E2;                     // 512
  int* gbase  = gcnt + 512;                    // 512+1
  int* gbuk   = gbase + 513 + 2;               // nbuk*BUKPAD
  unsigned short* wfrag =
      (unsigned short*)(((uintptr_t)(gbuk + (size_t)nbuk * BUKPAD) + 15) & ~(uintptr_t)15);
  float* sums = (float*)(wfrag + 16384);       // NB*16
  float* cnts = sums + NB * CH2_;              // NB

  // ---- CSR build (2-pass bucketed counting sort) ----
  fill_f32<<<1, 256, 0, stream>>>((float*)gcnt, 0.0f, 512);
  bucket_scatter<<<(E2 + 8191) / 8192, 256, 0, stream>>>(ei, E, E2, gcnt, gbuk);
  bucket_prefix<<<1, 64, 0, stream>>>(gcnt, nbuk, gbase, irow, N);
  bucket_csr<<<nbuk, 256, 0, stream>>>(gcnt, gbase, gbuk, irow, icsr, N);

  // ---- layer 1 GEMM on matrix cores (xl bf16, xr fp32) ----
  build_wfrag<<<64, 256, 0, stream>>>(Wl1, Wr1, wfrag);
  gemm_mfma_l1<<<(N + 63) / 64, 256, 0, stream>>>(x, wfrag, bl1, br1, xl1, xr1, N);

  // ---- fused layer 1 + layer-2 linear transforms ----
  fused_layer1<<<(N + 3) / 4, 256, 0, stream>>>(
      irow, icsr, xl1, xr1, att1, bias1, Wl2, bl2, Wr2, br2, xl2, xr2, N);

  // ---- fused layer 2 ----
  fused_layer2<<<(N + 15) / 16, 256, 0, stream>>>(irow, icsr, xl2, xr2, att2, bias2, h2, N);

  // ---- pooling + classifier ----
  fill_f32<<<1, 256, 0, stream>>>(sums, 0.0f, NB * CH2_ + NB);
  pool_kernel<<<256, 256, 0, stream>>>(h2, batch, sums, cnts, N);
  classifier<<<1, 64, 0, stream>>>(sums, cnts, Wc, bc, out);
}